// Round 4
// baseline (285.904 us; speedup 1.0000x reference)
//
#include <hip/hip_runtime.h>
#include <hip/hip_bf16.h>
#include <stdint.h>
#include <cmath>

typedef __attribute__((ext_vector_type(8))) short short8;
typedef __attribute__((ext_vector_type(4))) float f32x4;
typedef __attribute__((ext_vector_type(4))) int i32x4;

#define D_MODEL 1024
#define S_LEN   2048
#define N_HEADS 16
#define HEAD_D  64
#define BATCH   2

__device__ __forceinline__ unsigned short f2bf(float f) {
  __hip_bfloat16 h = __float2bfloat16(f);
  return *reinterpret_cast<unsigned short*>(&h);
}

__device__ __forceinline__ unsigned int pack2(unsigned short lo, unsigned short hi) {
  return (unsigned int)lo | ((unsigned int)hi << 16);
}

// async global->LDS, 16B per lane. LDS base must be wave-uniform; HW adds lane*16.
__device__ __forceinline__ void gload_lds16(const void* g, void* l) {
  auto gp = (const __attribute__((address_space(1))) unsigned int*)(uintptr_t)g;
  auto lp = (__attribute__((address_space(3))) unsigned int*)(unsigned int)(uintptr_t)l;
  __builtin_amdgcn_global_load_lds(gp, lp, 16, 0, 0);
}

// ---------------- cast fp32 -> bf16 (vectorized) ----------------
__global__ void cast_f32_bf16(const float* __restrict__ in, unsigned short* __restrict__ out, int n4) {
  int i = blockIdx.x * blockDim.x + threadIdx.x;
  if (i >= n4) return;
  float4 v = reinterpret_cast<const float4*>(in)[i];
  ushort4 o;
  o.x = f2bf(v.x); o.y = f2bf(v.y); o.z = f2bf(v.z); o.w = f2bf(v.w);
  reinterpret_cast<ushort4*>(out)[i] = o;
}

// ---------------- transpose + cast: out[C][R] = bf16(in[R][C]) ----------------
__global__ void transpose_cast(const float* __restrict__ in, unsigned short* __restrict__ out, int R, int C) {
  __shared__ float tile[32][33];
  int c0 = blockIdx.x * 32, r0 = blockIdx.y * 32;
  int tx = threadIdx.x, ty = threadIdx.y;  // blockDim (32,8)
#pragma unroll
  for (int j = 0; j < 32; j += 8)
    tile[ty + j][tx] = in[(size_t)(r0 + ty + j) * C + c0 + tx];
  __syncthreads();
#pragma unroll
  for (int j = 0; j < 32; j += 8)
    out[(size_t)(c0 + ty + j) * R + r0 + tx] = f2bf(tile[tx][ty + j]);
}

// ---------------- bf16 GEMM, C = A * BT^T   (A[M,K], BT[N,K]) ----------------
// m97 structure: 128x128 tile, BK=32, 4 waves, 4x4 16x16x32 fragments/wave,
// global_load_lds width-16 staging.
template <typename OutT>
__global__ __launch_bounds__(256) void gemm_bt(
    const unsigned short* __restrict__ A,
    const unsigned short* __restrict__ BT,
    OutT* __restrict__ C,
    int M, int N, int K)
{
  constexpr int BK = 32;
  __shared__ unsigned short As[128 * BK];
  __shared__ unsigned short Bs[128 * BK];
  const int tid = threadIdx.x;
  const int wave = tid >> 6, lane = tid & 63;
  const int l15 = lane & 15, l4 = lane >> 4;
  const int wr = wave >> 1, wc = wave & 1;
  const size_t m0 = (size_t)blockIdx.y * 128, n0 = (size_t)blockIdx.x * 128;

  f32x4 acc[4][4];
#pragma unroll
  for (int m = 0; m < 4; ++m)
#pragma unroll
    for (int n = 0; n < 4; ++n) acc[m][n] = 0.f;

  for (int k0 = 0; k0 < K; k0 += BK) {
    __syncthreads();
#pragma unroll
    for (int it = 0; it < 2; ++it) {
      const int base = it * 256 + wave * 64;         // wave-uniform chunk base
      const int chunk = base + lane;                  // per-lane chunk
      const int row = chunk >> 2, k8 = (chunk & 3) * 8;
      gload_lds16(A + (m0 + row) * K + k0 + k8, &As[base * 8]);
      gload_lds16(BT + (n0 + row) * K + k0 + k8, &Bs[base * 8]);
    }
    __syncthreads();
    short8 af[4], bfr[4];
#pragma unroll
    for (int m = 0; m < 4; ++m)
      af[m] = *reinterpret_cast<const short8*>(&As[(wr * 64 + m * 16 + l15) * BK + l4 * 8]);
#pragma unroll
    for (int n = 0; n < 4; ++n)
      bfr[n] = *reinterpret_cast<const short8*>(&Bs[(wc * 64 + n * 16 + l15) * BK + l4 * 8]);
#pragma unroll
    for (int m = 0; m < 4; ++m)
#pragma unroll
      for (int n = 0; n < 4; ++n)
        acc[m][n] = __builtin_amdgcn_mfma_f32_16x16x32_bf16(af[m], bfr[n], acc[m][n], 0, 0, 0);
  }

  // C layout: col = lane&15, row = (lane>>4)*4 + reg   [m89-verified]
#pragma unroll
  for (int m = 0; m < 4; ++m)
#pragma unroll
    for (int n = 0; n < 4; ++n)
#pragma unroll
      for (int r = 0; r < 4; ++r) {
        size_t row = m0 + wr * 64 + m * 16 + l4 * 4 + r;
        size_t col = n0 + wc * 64 + n * 16 + l15;
        if constexpr (sizeof(OutT) == 2)
          C[row * N + col] = (OutT)f2bf(acc[m][n][r]);
        else
          C[row * N + col] = acc[m][n][r];
      }
}

// ---------------- causal flash attention ----------------
// grid: (S/64, B*H). block: 256 (4 waves), each wave owns 16 q rows.
// T14 async-STAGE: tile t+1's K/V global loads issued right after tile t's
// LDS writes so HBM/L2 latency hides under tile t's compute.
// V staging: each thread handles 2 kv rows x 8 d, writes packed ushort2
// (8 x ds_write_b32 instead of 16 x ds_write_b16, same bank profile).
__global__ __launch_bounds__(256) void attn_kernel(
    const unsigned short* __restrict__ qkv,  // [B*S, 3*D] bf16
    unsigned short* __restrict__ ctx)        // [B*S, D]   bf16
{
  constexpr int LDT = 72;  // padded row; rows stay 16B-aligned (144B)
  __shared__ unsigned short Ks[64 * LDT];
  __shared__ unsigned short Vt[64 * LDT];   // transposed: Vt[d][kv]
  __shared__ unsigned short Ps[64 * LDT];

  const int tid = threadIdx.x;
  const int wave = tid >> 6, lane = tid & 63;
  const int l15 = lane & 15, l4 = lane >> 4;
  const int qt = blockIdx.x;
  const int bh = blockIdx.y;
  const int b = bh >> 4, h = bh & 15;
  const int q0 = qt * 64;
  const size_t rowstride = 3 * D_MODEL;
  const size_t bbase = (size_t)b * S_LEN;

  // Q fragments held in registers for the whole loop (A-frag: row=l15, k=(l>>4)*8+j)
  short8 qf[2];
  {
    const int qrow = q0 + wave * 16 + l15;
    const unsigned short* qp = qkv + (bbase + qrow) * rowstride + h * HEAD_D;
    qf[0] = *reinterpret_cast<const short8*>(qp + l4 * 8);
    qf[1] = *reinterpret_cast<const short8*>(qp + 32 + l4 * 8);
  }

  f32x4 o[4];
#pragma unroll
  for (int nf = 0; nf < 4; ++nf) o[nf] = 0.f;
  float m_run[4], l_run[4];
#pragma unroll
  for (int r = 0; r < 4; ++r) { m_run[r] = -INFINITY; l_run[r] = 0.f; }

  const int nt = qt + 1;            // causal: only tiles with kv0 <= q_max
  // K staging indices: row sr_k = tid>>2, cols sck..sck+15
  const int sr_k = tid >> 2;
  const int sck  = (tid & 3) * 16;
  // V staging indices: rows kvr, kvr+1, cols 8a..8a+7
  const int kvr = (tid >> 3) * 2;
  const int a8  = (tid & 7) * 8;

  const unsigned short* kbase = qkv + bbase * rowstride + h * HEAD_D + D_MODEL;
  const unsigned short* vbase = qkv + bbase * rowstride + h * HEAD_D + 2 * D_MODEL;

  // prologue: load tile 0 K/V into registers
  short8 kr0, kr1, vr0, vr1;
  {
    const unsigned short* kp = kbase + (size_t)sr_k * rowstride + sck;
    const unsigned short* vp = vbase + (size_t)kvr * rowstride + a8;
    kr0 = *reinterpret_cast<const short8*>(kp);
    kr1 = *reinterpret_cast<const short8*>(kp + 8);
    vr0 = *reinterpret_cast<const short8*>(vp);
    vr1 = *reinterpret_cast<const short8*>(vp + rowstride);
  }

  for (int t = 0; t < nt; ++t) {
    const int kv0 = t * 64;
    __syncthreads();  // prev tile's consumers done with Ks/Vt/Ps

    // write staged registers -> LDS
    *reinterpret_cast<short8*>(&Ks[sr_k * LDT + sck])     = kr0;
    *reinterpret_cast<short8*>(&Ks[sr_k * LDT + sck + 8]) = kr1;
#pragma unroll
    for (int j = 0; j < 8; ++j)
      *reinterpret_cast<unsigned int*>(&Vt[(a8 + j) * LDT + kvr]) =
          pack2((unsigned short)vr0[j], (unsigned short)vr1[j]);

    // issue next tile's loads (fly during compute below)
    if (t + 1 < nt) {
      const unsigned short* kp = kbase + (size_t)(kv0 + 64 + sr_k) * rowstride + sck;
      const unsigned short* vp = vbase + (size_t)(kv0 + 64 + kvr) * rowstride + a8;
      kr0 = *reinterpret_cast<const short8*>(kp);
      kr1 = *reinterpret_cast<const short8*>(kp + 8);
      vr0 = *reinterpret_cast<const short8*>(vp);
      vr1 = *reinterpret_cast<const short8*>(vp + rowstride);
    }
    __syncthreads();

    // S = Q K^T : 16(q) x 64(kv), B-frag from Ks rows
    f32x4 accs[4];
#pragma unroll
    for (int nf = 0; nf < 4; ++nf) accs[nf] = 0.f;
    __builtin_amdgcn_s_setprio(1);
#pragma unroll
    for (int nf = 0; nf < 4; ++nf) {
      short8 kf0 = *reinterpret_cast<const short8*>(&Ks[(nf * 16 + l15) * LDT + l4 * 8]);
      short8 kf1 = *reinterpret_cast<const short8*>(&Ks[(nf * 16 + l15) * LDT + 32 + l4 * 8]);
      accs[nf] = __builtin_amdgcn_mfma_f32_16x16x32_bf16(qf[0], kf0, accs[nf], 0, 0, 0);
      accs[nf] = __builtin_amdgcn_mfma_f32_16x16x32_bf16(qf[1], kf1, accs[nf], 0, 0, 0);
    }
    __builtin_amdgcn_s_setprio(0);

    // scale + causal mask; online softmax (16-lane shfl reductions)
    float p[4][4], tm[4];
    const int qrow_base = q0 + wave * 16 + l4 * 4;
#pragma unroll
    for (int r = 0; r < 4; ++r) tm[r] = -INFINITY;
#pragma unroll
    for (int nf = 0; nf < 4; ++nf) {
      int kv = kv0 + nf * 16 + l15;
#pragma unroll
      for (int r = 0; r < 4; ++r) {
        float v = accs[nf][r] * 0.125f;
        if (kv > qrow_base + r) v = -INFINITY;
        p[nf][r] = v;
        tm[r] = fmaxf(tm[r], v);
      }
    }
#pragma unroll
    for (int mset = 1; mset < 16; mset <<= 1)
#pragma unroll
      for (int r = 0; r < 4; ++r)
        tm[r] = fmaxf(tm[r], __shfl_xor(tm[r], mset));
    float corr[4], ts[4];
#pragma unroll
    for (int r = 0; r < 4; ++r) {
      float mn = fmaxf(m_run[r], tm[r]);
      corr[r] = __expf(m_run[r] - mn);
      m_run[r] = mn;
      ts[r] = 0.f;
    }
#pragma unroll
    for (int nf = 0; nf < 4; ++nf)
#pragma unroll
      for (int r = 0; r < 4; ++r) {
        float e = __expf(p[nf][r] - m_run[r]);
        p[nf][r] = e;
        ts[r] += e;
      }
#pragma unroll
    for (int mset = 1; mset < 16; mset <<= 1)
#pragma unroll
      for (int r = 0; r < 4; ++r)
        ts[r] += __shfl_xor(ts[r], mset);
#pragma unroll
    for (int r = 0; r < 4; ++r) l_run[r] = l_run[r] * corr[r] + ts[r];
#pragma unroll
    for (int nf = 0; nf < 4; ++nf)
#pragma unroll
      for (int r = 0; r < 4; ++r)
        o[nf][r] *= corr[r];

    // P -> LDS (C-layout scatter), then consume as A-fragments
#pragma unroll
    for (int nf = 0; nf < 4; ++nf)
#pragma unroll
      for (int r = 0; r < 4; ++r)
        Ps[(wave * 16 + l4 * 4 + r) * LDT + nf * 16 + l15] = f2bf(p[nf][r]);
    __syncthreads();

    // O += P V
    __builtin_amdgcn_s_setprio(1);
#pragma unroll
    for (int c = 0; c < 2; ++c) {
      short8 pa = *reinterpret_cast<const short8*>(&Ps[(wave * 16 + l15) * LDT + c * 32 + l4 * 8]);
#pragma unroll
      for (int nf = 0; nf < 4; ++nf) {
        short8 vbf = *reinterpret_cast<const short8*>(&Vt[(nf * 16 + l15) * LDT + c * 32 + l4 * 8]);
        o[nf] = __builtin_amdgcn_mfma_f32_16x16x32_bf16(pa, vbf, o[nf], 0, 0, 0);
      }
    }
    __builtin_amdgcn_s_setprio(0);
  }

  // epilogue: O /= l, write bf16 ctx
#pragma unroll
  for (int r = 0; r < 4; ++r) {
    float inv = 1.f / l_run[r];
    const int q = q0 + wave * 16 + l4 * 4 + r;
    unsigned short* op = ctx + (bbase + q) * D_MODEL + h * HEAD_D;
#pragma unroll
    for (int nf = 0; nf < 4; ++nf)
      op[nf * 16 + l15] = f2bf(o[nf][r] * inv);
  }
}

// ---------------- launch ----------------
extern "C" void kernel_launch(void* const* d_in, const int* in_sizes, int n_in,
                              void* d_out, int out_size, void* d_ws, size_t ws_size,
                              hipStream_t stream) {
  const float* x     = (const float*)d_in[0];
  const float* w_qkv = (const float*)d_in[1];
  const float* w_out = (const float*)d_in[2];
  float* out = (float*)d_out;

  char* p = (char*)d_ws;
  unsigned short* xb    = (unsigned short*)p; p += (size_t)4096 * 1024 * 2;
  unsigned short* wqkvT = (unsigned short*)p; p += (size_t)3072 * 1024 * 2;
  unsigned short* woutT = (unsigned short*)p; p += (size_t)1024 * 1024 * 2;
  unsigned short* qkv   = (unsigned short*)p; p += (size_t)4096 * 3072 * 2;
  unsigned short* ctx   = (unsigned short*)p; p += (size_t)4096 * 1024 * 2;

  cast_f32_bf16<<<4096, 256, 0, stream>>>(x, xb, 4096 * 1024 / 4);
  transpose_cast<<<dim3(3072 / 32, 1024 / 32), dim3(32, 8), 0, stream>>>(w_qkv, wqkvT, 1024, 3072);
  transpose_cast<<<dim3(1024 / 32, 1024 / 32), dim3(32, 8), 0, stream>>>(w_out, woutT, 1024, 1024);
  gemm_bt<unsigned short><<<dim3(3072 / 128, 4096 / 128), 256, 0, stream>>>(xb, wqkvT, qkv, 4096, 3072, 1024);
  attn_kernel<<<dim3(S_LEN / 64, BATCH * N_HEADS), 256, 0, stream>>>(qkv, ctx);
  gemm_bt<float><<<dim3(1024 / 128, 4096 / 128), 256, 0, stream>>>(ctx, woutT, out, 4096, 1024, 1024);
}

// Round 6
// 283.103 us; speedup vs baseline: 1.0099x; 1.0099x over previous
//
#include <hip/hip_runtime.h>
#include <hip/hip_bf16.h>
#include <stdint.h>
#include <cmath>

typedef __attribute__((ext_vector_type(8))) short short8;
typedef __attribute__((ext_vector_type(4))) float f32x4;
typedef __attribute__((ext_vector_type(4))) int i32x4;

#define D_MODEL 1024
#define S_LEN   2048
#define N_HEADS 16
#define HEAD_D  64
#define BATCH   2

__device__ __forceinline__ unsigned short f2bf(float f) {
  __hip_bfloat16 h = __float2bfloat16(f);
  return *reinterpret_cast<unsigned short*>(&h);
}

__device__ __forceinline__ float bf2f(unsigned short u) {
  unsigned int b = ((unsigned int)u) << 16;
  return *reinterpret_cast<float*>(&b);
}

__device__ __forceinline__ unsigned int pack2(unsigned short lo, unsigned short hi) {
  return (unsigned int)lo | ((unsigned int)hi << 16);
}

// async global->LDS, 16B per lane. LDS base must be wave-uniform; HW adds lane*16.
__device__ __forceinline__ void gload_lds16(const void* g, void* l) {
  auto gp = (const __attribute__((address_space(1))) unsigned int*)(uintptr_t)g;
  auto lp = (__attribute__((address_space(3))) unsigned int*)(unsigned int)(uintptr_t)l;
  __builtin_amdgcn_global_load_lds(gp, lp, 16, 0, 0);
}

// ---------------- cast fp32 -> bf16 (vectorized) ----------------
__global__ void cast_f32_bf16(const float* __restrict__ in, unsigned short* __restrict__ out, int n4) {
  int i = blockIdx.x * blockDim.x + threadIdx.x;
  if (i >= n4) return;
  float4 v = reinterpret_cast<const float4*>(in)[i];
  ushort4 o;
  o.x = f2bf(v.x); o.y = f2bf(v.y); o.z = f2bf(v.z); o.w = f2bf(v.w);
  reinterpret_cast<ushort4*>(out)[i] = o;
}

// ---------------- transpose + cast: out[C][R] = bf16(in[R][C]) ----------------
__global__ void transpose_cast(const float* __restrict__ in, unsigned short* __restrict__ out, int R, int C) {
  __shared__ float tile[32][33];
  int c0 = blockIdx.x * 32, r0 = blockIdx.y * 32;
  int tx = threadIdx.x, ty = threadIdx.y;  // blockDim (32,8)
#pragma unroll
  for (int j = 0; j < 32; j += 8)
    tile[ty + j][tx] = in[(size_t)(r0 + ty + j) * C + c0 + tx];
  __syncthreads();
#pragma unroll
  for (int j = 0; j < 32; j += 8)
    out[(size_t)(c0 + ty + j) * R + r0 + tx] = f2bf(tile[tx][ty + j]);
}

// ---------------- bf16 GEMM, C = A * BT^T   (A[M,K], BT[N,K]) ----------------
template <typename OutT>
__global__ __launch_bounds__(256) void gemm_bt(
    const unsigned short* __restrict__ A,
    const unsigned short* __restrict__ BT,
    OutT* __restrict__ C,
    int M, int N, int K)
{
  constexpr int BK = 32;
  __shared__ unsigned short As[128 * BK];
  __shared__ unsigned short Bs[128 * BK];
  const int tid = threadIdx.x;
  const int wave = tid >> 6, lane = tid & 63;
  const int l15 = lane & 15, l4 = lane >> 4;
  const int wr = wave >> 1, wc = wave & 1;
  const size_t m0 = (size_t)blockIdx.y * 128, n0 = (size_t)blockIdx.x * 128;

  f32x4 acc[4][4];
#pragma unroll
  for (int m = 0; m < 4; ++m)
#pragma unroll
    for (int n = 0; n < 4; ++n) acc[m][n] = 0.f;

  for (int k0 = 0; k0 < K; k0 += BK) {
    __syncthreads();
#pragma unroll
    for (int it = 0; it < 2; ++it) {
      const int base = it * 256 + wave * 64;         // wave-uniform chunk base
      const int chunk = base + lane;                  // per-lane chunk
      const int row = chunk >> 2, k8 = (chunk & 3) * 8;
      gload_lds16(A + (m0 + row) * K + k0 + k8, &As[base * 8]);
      gload_lds16(BT + (n0 + row) * K + k0 + k8, &Bs[base * 8]);
    }
    __syncthreads();
    short8 af[4], bfr[4];
#pragma unroll
    for (int m = 0; m < 4; ++m)
      af[m] = *reinterpret_cast<const short8*>(&As[(wr * 64 + m * 16 + l15) * BK + l4 * 8]);
#pragma unroll
    for (int n = 0; n < 4; ++n)
      bfr[n] = *reinterpret_cast<const short8*>(&Bs[(wc * 64 + n * 16 + l15) * BK + l4 * 8]);
#pragma unroll
    for (int m = 0; m < 4; ++m)
#pragma unroll
      for (int n = 0; n < 4; ++n)
        acc[m][n] = __builtin_amdgcn_mfma_f32_16x16x32_bf16(af[m], bfr[n], acc[m][n], 0, 0, 0);
  }

  // C layout: col = lane&15, row = (lane>>4)*4 + reg   [m89-verified]
#pragma unroll
  for (int m = 0; m < 4; ++m)
#pragma unroll
    for (int n = 0; n < 4; ++n)
#pragma unroll
      for (int r = 0; r < 4; ++r) {
        size_t row = m0 + wr * 64 + m * 16 + l4 * 4 + r;
        size_t col = n0 + wc * 64 + n * 16 + l15;
        if constexpr (sizeof(OutT) == 2)
          C[row * N + col] = (OutT)f2bf(acc[m][n][r]);
        else
          C[row * N + col] = acc[m][n][r];
      }
}

// ---------------- causal flash attention ----------------
// grid: (S/64, B*H). block: 256 (4 waves), each wave owns 16 q rows.
// LPT: qt = 31 - blockIdx.x so the heaviest (most-KV-tiles) blocks launch
// first -> greedy CU scheduling packs small blocks into the tail.
// Scale 1/8 folded into Q regs (exact exponent shift). Causal mask applied
// only on the diagonal tile (t == qt); interior tiles skip the cndmask work.
__global__ __launch_bounds__(256) void attn_kernel(
    const unsigned short* __restrict__ qkv,  // [B*S, 3*D] bf16
    unsigned short* __restrict__ ctx)        // [B*S, D]   bf16
{
  constexpr int LDT = 72;  // padded row; rows stay 16B-aligned (144B)
  __shared__ unsigned short Ks[64 * LDT];
  __shared__ unsigned short Vt[64 * LDT];   // transposed: Vt[d][kv]
  __shared__ unsigned short Ps[64 * LDT];

  const int tid = threadIdx.x;
  const int wave = tid >> 6, lane = tid & 63;
  const int l15 = lane & 15, l4 = lane >> 4;
  const int qt = (int)gridDim.x - 1 - (int)blockIdx.x;   // LPT order
  const int bh = blockIdx.y;
  const int b = bh >> 4, h = bh & 15;
  const int q0 = qt * 64;
  const size_t rowstride = 3 * D_MODEL;
  const size_t bbase = (size_t)b * S_LEN;

  // Q fragments in registers for the whole loop, pre-scaled by 1/8 (exact).
  short8 qf[2];
  {
    const int qrow = q0 + wave * 16 + l15;
    const unsigned short* qp = qkv + (bbase + qrow) * rowstride + h * HEAD_D;
    qf[0] = *reinterpret_cast<const short8*>(qp + l4 * 8);
    qf[1] = *reinterpret_cast<const short8*>(qp + 32 + l4 * 8);
#pragma unroll
    for (int j = 0; j < 8; ++j) {
      qf[0][j] = (short)f2bf(bf2f((unsigned short)qf[0][j]) * 0.125f);
      qf[1][j] = (short)f2bf(bf2f((unsigned short)qf[1][j]) * 0.125f);
    }
  }

  f32x4 o[4];
#pragma unroll
  for (int nf = 0; nf < 4; ++nf) o[nf] = 0.f;
  float m_run[4], l_run[4];
#pragma unroll
  for (int r = 0; r < 4; ++r) { m_run[r] = -INFINITY; l_run[r] = 0.f; }

  const int nt = qt + 1;            // causal: only tiles with kv0 <= q_max
  // K staging indices: row sr_k = tid>>2, cols sck..sck+15
  const int sr_k = tid >> 2;
  const int sck  = (tid & 3) * 16;
  // V staging indices: rows kvr, kvr+1, cols a8..a8+7
  const int kvr = (tid >> 3) * 2;
  const int a8  = (tid & 7) * 8;

  const unsigned short* kbase = qkv + bbase * rowstride + h * HEAD_D + D_MODEL;
  const unsigned short* vbase = qkv + bbase * rowstride + h * HEAD_D + 2 * D_MODEL;

  // prologue: load tile 0 K/V into registers
  short8 kr0, kr1, vr0, vr1;
  {
    const unsigned short* kp = kbase + (size_t)sr_k * rowstride + sck;
    const unsigned short* vp = vbase + (size_t)kvr * rowstride + a8;
    kr0 = *reinterpret_cast<const short8*>(kp);
    kr1 = *reinterpret_cast<const short8*>(kp + 8);
    vr0 = *reinterpret_cast<const short8*>(vp);
    vr1 = *reinterpret_cast<const short8*>(vp + rowstride);
  }

  for (int t = 0; t < nt; ++t) {
    const int kv0 = t * 64;
    __syncthreads();  // prev tile's consumers done with Ks/Vt/Ps

    // write staged registers -> LDS
    *reinterpret_cast<short8*>(&Ks[sr_k * LDT + sck])     = kr0;
    *reinterpret_cast<short8*>(&Ks[sr_k * LDT + sck + 8]) = kr1;
#pragma unroll
    for (int j = 0; j < 8; ++j)
      *reinterpret_cast<unsigned int*>(&Vt[(a8 + j) * LDT + kvr]) =
          pack2((unsigned short)vr0[j], (unsigned short)vr1[j]);

    // issue next tile's loads (fly during compute below)
    if (t + 1 < nt) {
      const unsigned short* kp = kbase + (size_t)(kv0 + 64 + sr_k) * rowstride + sck;
      const unsigned short* vp = vbase + (size_t)(kv0 + 64 + kvr) * rowstride + a8;
      kr0 = *reinterpret_cast<const short8*>(kp);
      kr1 = *reinterpret_cast<const short8*>(kp + 8);
      vr0 = *reinterpret_cast<const short8*>(vp);
      vr1 = *reinterpret_cast<const short8*>(vp + rowstride);
    }
    __syncthreads();

    // S = Q K^T : 16(q) x 64(kv), B-frag from Ks rows
    f32x4 accs[4];
#pragma unroll
    for (int nf = 0; nf < 4; ++nf) accs[nf] = 0.f;
    __builtin_amdgcn_s_setprio(1);
#pragma unroll
    for (int nf = 0; nf < 4; ++nf) {
      short8 kf0 = *reinterpret_cast<const short8*>(&Ks[(nf * 16 + l15) * LDT + l4 * 8]);
      short8 kf1 = *reinterpret_cast<const short8*>(&Ks[(nf * 16 + l15) * LDT + 32 + l4 * 8]);
      accs[nf] = __builtin_amdgcn_mfma_f32_16x16x32_bf16(qf[0], kf0, accs[nf], 0, 0, 0);
      accs[nf] = __builtin_amdgcn_mfma_f32_16x16x32_bf16(qf[1], kf1, accs[nf], 0, 0, 0);
    }
    __builtin_amdgcn_s_setprio(0);

    // online softmax (16-lane shfl reductions); mask only on diagonal tile
    float p[4][4], tm[4];
    const int qrow_base = q0 + wave * 16 + l4 * 4;
#pragma unroll
    for (int r = 0; r < 4; ++r) tm[r] = -INFINITY;
    if (t == qt) {
#pragma unroll
      for (int nf = 0; nf < 4; ++nf) {
        int kv = kv0 + nf * 16 + l15;
#pragma unroll
        for (int r = 0; r < 4; ++r) {
          float v = accs[nf][r];
          if (kv > qrow_base + r) v = -INFINITY;
          p[nf][r] = v;
          tm[r] = fmaxf(tm[r], v);
        }
      }
    } else {
#pragma unroll
      for (int nf = 0; nf < 4; ++nf)
#pragma unroll
        for (int r = 0; r < 4; ++r) {
          float v = accs[nf][r];
          p[nf][r] = v;
          tm[r] = fmaxf(tm[r], v);
        }
    }
#pragma unroll
    for (int mset = 1; mset < 16; mset <<= 1)
#pragma unroll
      for (int r = 0; r < 4; ++r)
        tm[r] = fmaxf(tm[r], __shfl_xor(tm[r], mset));
    float corr[4], ts[4];
#pragma unroll
    for (int r = 0; r < 4; ++r) {
      float mn = fmaxf(m_run[r], tm[r]);
      corr[r] = __expf(m_run[r] - mn);
      m_run[r] = mn;
      ts[r] = 0.f;
    }
#pragma unroll
    for (int nf = 0; nf < 4; ++nf)
#pragma unroll
      for (int r = 0; r < 4; ++r) {
        float e = __expf(p[nf][r] - m_run[r]);
        p[nf][r] = e;
        ts[r] += e;
      }
#pragma unroll
    for (int mset = 1; mset < 16; mset <<= 1)
#pragma unroll
      for (int r = 0; r < 4; ++r)
        ts[r] += __shfl_xor(ts[r], mset);
#pragma unroll
    for (int r = 0; r < 4; ++r) l_run[r] = l_run[r] * corr[r] + ts[r];
#pragma unroll
    for (int nf = 0; nf < 4; ++nf)
#pragma unroll
      for (int r = 0; r < 4; ++r)
        o[nf][r] *= corr[r];

    // P -> LDS (C-layout scatter), then consume as A-fragments
#pragma unroll
    for (int nf = 0; nf < 4; ++nf)
#pragma unroll
      for (int r = 0; r < 4; ++r)
        Ps[(wave * 16 + l4 * 4 + r) * LDT + nf * 16 + l15] = f2bf(p[nf][r]);
    __syncthreads();

    // O += P V
    __builtin_amdgcn_s_setprio(1);
#pragma unroll
    for (int c = 0; c < 2; ++c) {
      short8 pa = *reinterpret_cast<const short8*>(&Ps[(wave * 16 + l15) * LDT + c * 32 + l4 * 8]);
#pragma unroll
      for (int nf = 0; nf < 4; ++nf) {
        short8 vbf = *reinterpret_cast<const short8*>(&Vt[(nf * 16 + l15) * LDT + c * 32 + l4 * 8]);
        o[nf] = __builtin_amdgcn_mfma_f32_16x16x32_bf16(pa, vbf, o[nf], 0, 0, 0);
      }
    }
    __builtin_amdgcn_s_setprio(0);
  }

  // epilogue: O /= l, write bf16 ctx
#pragma unroll
  for (int r = 0; r < 4; ++r) {
    float inv = 1.f / l_run[r];
    const int q = q0 + wave * 16 + l4 * 4 + r;
    unsigned short* op = ctx + (bbase + q) * D_MODEL + h * HEAD_D;
#pragma unroll
    for (int nf = 0; nf < 4; ++nf)
      op[nf * 16 + l15] = f2bf(o[nf][r] * inv);
  }
}

// ---------------- launch ----------------
extern "C" void kernel_launch(void* const* d_in, const int* in_sizes, int n_in,
                              void* d_out, int out_size, void* d_ws, size_t ws_size,
                              hipStream_t stream) {
  const float* x     = (const float*)d_in[0];
  const float* w_qkv = (const float*)d_in[1];
  const float* w_out = (const float*)d_in[2];
  float* out = (float*)d_out;

  char* p = (char*)d_ws;
  unsigned short* xb    = (unsigned short*)p; p += (size_t)4096 * 1024 * 2;
  unsigned short* wqkvT = (unsigned short*)p; p += (size_t)3072 * 1024 * 2;
  unsigned short* woutT = (unsigned short*)p; p += (size_t)1024 * 1024 * 2;
  unsigned short* qkv   = (unsigned short*)p; p += (size_t)4096 * 3072 * 2;
  unsigned short* ctx   = (unsigned short*)p; p += (size_t)4096 * 1024 * 2;

  cast_f32_bf16<<<4096, 256, 0, stream>>>(x, xb, 4096 * 1024 / 4);
  transpose_cast<<<dim3(3072 / 32, 1024 / 32), dim3(32, 8), 0, stream>>>(w_qkv, wqkvT, 1024, 3072);
  transpose_cast<<<dim3(1024 / 32, 1024 / 32), dim3(32, 8), 0, stream>>>(w_out, woutT, 1024, 1024);
  gemm_bt<unsigned short><<<dim3(3072 / 128, 4096 / 128), 256, 0, stream>>>(xb, wqkvT, qkv, 4096, 3072, 1024);
  attn_kernel<<<dim3(S_LEN / 64, BATCH * N_HEADS), 256, 0, stream>>>(qkv, ctx);
  gemm_bt<float><<<dim3(1024 / 128, 4096 / 128), 256, 0, stream>>>(ctx, woutT, out, 4096, 1024, 1024);
}

// Round 7
// 266.792 us; speedup vs baseline: 1.0716x; 1.0611x over previous
//
#include <hip/hip_runtime.h>
#include <hip/hip_bf16.h>
#include <stdint.h>
#include <cmath>

typedef __attribute__((ext_vector_type(8))) short short8;
typedef __attribute__((ext_vector_type(4))) float f32x4;
typedef __attribute__((ext_vector_type(4))) int i32x4;

#define D_MODEL 1024
#define S_LEN   2048
#define N_HEADS 16
#define HEAD_D  64
#define BATCH   2

__device__ __forceinline__ unsigned short f2bf(float f) {
  __hip_bfloat16 h = __float2bfloat16(f);
  return *reinterpret_cast<unsigned short*>(&h);
}

__device__ __forceinline__ float bf2f(unsigned short u) {
  unsigned int b = ((unsigned int)u) << 16;
  return *reinterpret_cast<float*>(&b);
}

__device__ __forceinline__ unsigned int pack2(unsigned short lo, unsigned short hi) {
  return (unsigned int)lo | ((unsigned int)hi << 16);
}

// async global->LDS, 16B per lane. LDS base must be wave-uniform; HW adds lane*16.
__device__ __forceinline__ void gload_lds16(const void* g, void* l) {
  auto gp = (const __attribute__((address_space(1))) unsigned int*)(uintptr_t)g;
  auto lp = (__attribute__((address_space(3))) unsigned int*)(unsigned int)(uintptr_t)l;
  __builtin_amdgcn_global_load_lds(gp, lp, 16, 0, 0);
}

// ---------------- cast fp32 -> bf16 (vectorized) ----------------
__global__ void cast_f32_bf16(const float* __restrict__ in, unsigned short* __restrict__ out, int n4) {
  int i = blockIdx.x * blockDim.x + threadIdx.x;
  if (i >= n4) return;
  float4 v = reinterpret_cast<const float4*>(in)[i];
  ushort4 o;
  o.x = f2bf(v.x); o.y = f2bf(v.y); o.z = f2bf(v.z); o.w = f2bf(v.w);
  reinterpret_cast<ushort4*>(out)[i] = o;
}

// ---------------- transpose + cast: out[C][R] = bf16(in[R][C]) ----------------
__global__ void transpose_cast(const float* __restrict__ in, unsigned short* __restrict__ out, int R, int C) {
  __shared__ float tile[32][33];
  int c0 = blockIdx.x * 32, r0 = blockIdx.y * 32;
  int tx = threadIdx.x, ty = threadIdx.y;  // blockDim (32,8)
#pragma unroll
  for (int j = 0; j < 32; j += 8)
    tile[ty + j][tx] = in[(size_t)(r0 + ty + j) * C + c0 + tx];
  __syncthreads();
#pragma unroll
  for (int j = 0; j < 32; j += 8)
    out[(size_t)(c0 + ty + j) * R + r0 + tx] = f2bf(tile[tx][ty + j]);
}

// ---------------- bf16 GEMM, C = A * BT^T   (A[M,K], BT[N,K]) ----------------
template <typename OutT>
__global__ __launch_bounds__(256) void gemm_bt(
    const unsigned short* __restrict__ A,
    const unsigned short* __restrict__ BT,
    OutT* __restrict__ C,
    int M, int N, int K)
{
  constexpr int BK = 32;
  __shared__ unsigned short As[128 * BK];
  __shared__ unsigned short Bs[128 * BK];
  const int tid = threadIdx.x;
  const int wave = tid >> 6, lane = tid & 63;
  const int l15 = lane & 15, l4 = lane >> 4;
  const int wr = wave >> 1, wc = wave & 1;
  const size_t m0 = (size_t)blockIdx.y * 128, n0 = (size_t)blockIdx.x * 128;

  f32x4 acc[4][4];
#pragma unroll
  for (int m = 0; m < 4; ++m)
#pragma unroll
    for (int n = 0; n < 4; ++n) acc[m][n] = 0.f;

  for (int k0 = 0; k0 < K; k0 += BK) {
    __syncthreads();
#pragma unroll
    for (int it = 0; it < 2; ++it) {
      const int base = it * 256 + wave * 64;         // wave-uniform chunk base
      const int chunk = base + lane;                  // per-lane chunk
      const int row = chunk >> 2, k8 = (chunk & 3) * 8;
      gload_lds16(A + (m0 + row) * K + k0 + k8, &As[base * 8]);
      gload_lds16(BT + (n0 + row) * K + k0 + k8, &Bs[base * 8]);
    }
    __syncthreads();
    short8 af[4], bfr[4];
#pragma unroll
    for (int m = 0; m < 4; ++m)
      af[m] = *reinterpret_cast<const short8*>(&As[(wr * 64 + m * 16 + l15) * BK + l4 * 8]);
#pragma unroll
    for (int n = 0; n < 4; ++n)
      bfr[n] = *reinterpret_cast<const short8*>(&Bs[(wc * 64 + n * 16 + l15) * BK + l4 * 8]);
#pragma unroll
    for (int m = 0; m < 4; ++m)
#pragma unroll
      for (int n = 0; n < 4; ++n)
        acc[m][n] = __builtin_amdgcn_mfma_f32_16x16x32_bf16(af[m], bfr[n], acc[m][n], 0, 0, 0);
  }

  // C layout: col = lane&15, row = (lane>>4)*4 + reg   [m89-verified]
#pragma unroll
  for (int m = 0; m < 4; ++m)
#pragma unroll
    for (int n = 0; n < 4; ++n)
#pragma unroll
      for (int r = 0; r < 4; ++r) {
        size_t row = m0 + wr * 64 + m * 16 + l4 * 4 + r;
        size_t col = n0 + wc * 64 + n * 16 + l15;
        if constexpr (sizeof(OutT) == 2)
          C[row * N + col] = (OutT)f2bf(acc[m][n][r]);
        else
          C[row * N + col] = acc[m][n][r];
      }
}

// ---------------- causal flash attention ----------------
// grid: (S/64, B*H). block: 256 (4 waves), each wave owns 16 q rows.
// Grid is fully resident (5 blocks/CU by LDS). Co-resident blocks are linear
// ids {i, i+256, i+512, i+768}, which share bx -> must NOT share qt. The
// swizzle qt = ((31-bx) + 8*(bh>>3)) & 31 gives co-resident qt offsets
// {0,8,16,24}: per-CU work 52..80 tile-units instead of 4..132.
// Scale 1/8 folded into Q regs. Mask only on the diagonal tile. Ps is
// wave-private -> no barrier between P-scatter and PV.
__global__ __launch_bounds__(256) void attn_kernel(
    const unsigned short* __restrict__ qkv,  // [B*S, 3*D] bf16
    unsigned short* __restrict__ ctx)        // [B*S, D]   bf16
{
  constexpr int LDT = 72;  // padded row; rows stay 16B-aligned (144B)
  __shared__ unsigned short Ks[64 * LDT];
  __shared__ unsigned short Vt[64 * LDT];   // transposed: Vt[d][kv]
  __shared__ unsigned short Ps[64 * LDT];

  const int tid = threadIdx.x;
  const int wave = tid >> 6, lane = tid & 63;
  const int l15 = lane & 15, l4 = lane >> 4;
  const int bh = blockIdx.y;
  const int qt = ((31 - (int)blockIdx.x) + ((bh >> 3) << 3)) & 31;  // CU-balance swizzle
  const int b = bh >> 4, h = bh & 15;
  const int q0 = qt * 64;
  const size_t rowstride = 3 * D_MODEL;
  const size_t bbase = (size_t)b * S_LEN;

  // Q fragments in registers for the whole loop, pre-scaled by 1/8 (exact).
  short8 qf[2];
  {
    const int qrow = q0 + wave * 16 + l15;
    const unsigned short* qp = qkv + (bbase + qrow) * rowstride + h * HEAD_D;
    qf[0] = *reinterpret_cast<const short8*>(qp + l4 * 8);
    qf[1] = *reinterpret_cast<const short8*>(qp + 32 + l4 * 8);
#pragma unroll
    for (int j = 0; j < 8; ++j) {
      qf[0][j] = (short)f2bf(bf2f((unsigned short)qf[0][j]) * 0.125f);
      qf[1][j] = (short)f2bf(bf2f((unsigned short)qf[1][j]) * 0.125f);
    }
  }

  f32x4 o[4];
#pragma unroll
  for (int nf = 0; nf < 4; ++nf) o[nf] = 0.f;
  float m_run[4], l_run[4];
#pragma unroll
  for (int r = 0; r < 4; ++r) { m_run[r] = -INFINITY; l_run[r] = 0.f; }

  const int nt = qt + 1;            // causal: only tiles with kv0 <= q_max
  // K staging indices: row sr_k = tid>>2, cols sck..sck+15
  const int sr_k = tid >> 2;
  const int sck  = (tid & 3) * 16;
  // V staging indices: rows kvr, kvr+1, cols a8..a8+7
  const int kvr = (tid >> 3) * 2;
  const int a8  = (tid & 7) * 8;

  const unsigned short* kbase = qkv + bbase * rowstride + h * HEAD_D + D_MODEL;
  const unsigned short* vbase = qkv + bbase * rowstride + h * HEAD_D + 2 * D_MODEL;

  // prologue: load tile 0 K/V into registers
  short8 kr0, kr1, vr0, vr1;
  {
    const unsigned short* kp = kbase + (size_t)sr_k * rowstride + sck;
    const unsigned short* vp = vbase + (size_t)kvr * rowstride + a8;
    kr0 = *reinterpret_cast<const short8*>(kp);
    kr1 = *reinterpret_cast<const short8*>(kp + 8);
    vr0 = *reinterpret_cast<const short8*>(vp);
    vr1 = *reinterpret_cast<const short8*>(vp + rowstride);
  }

  for (int t = 0; t < nt; ++t) {
    const int kv0 = t * 64;
    __syncthreads();  // prev tile's consumers done with Ks/Vt

    // write staged registers -> LDS
    *reinterpret_cast<short8*>(&Ks[sr_k * LDT + sck])     = kr0;
    *reinterpret_cast<short8*>(&Ks[sr_k * LDT + sck + 8]) = kr1;
#pragma unroll
    for (int j = 0; j < 8; ++j)
      *reinterpret_cast<unsigned int*>(&Vt[(a8 + j) * LDT + kvr]) =
          pack2((unsigned short)vr0[j], (unsigned short)vr1[j]);

    // issue next tile's loads (fly during compute below)
    if (t + 1 < nt) {
      const unsigned short* kp = kbase + (size_t)(kv0 + 64 + sr_k) * rowstride + sck;
      const unsigned short* vp = vbase + (size_t)(kv0 + 64 + kvr) * rowstride + a8;
      kr0 = *reinterpret_cast<const short8*>(kp);
      kr1 = *reinterpret_cast<const short8*>(kp + 8);
      vr0 = *reinterpret_cast<const short8*>(vp);
      vr1 = *reinterpret_cast<const short8*>(vp + rowstride);
    }
    __syncthreads();

    // S = Q K^T : 16(q) x 64(kv), B-frag from Ks rows
    f32x4 accs[4];
#pragma unroll
    for (int nf = 0; nf < 4; ++nf) accs[nf] = 0.f;
    __builtin_amdgcn_s_setprio(1);
#pragma unroll
    for (int nf = 0; nf < 4; ++nf) {
      short8 kf0 = *reinterpret_cast<const short8*>(&Ks[(nf * 16 + l15) * LDT + l4 * 8]);
      short8 kf1 = *reinterpret_cast<const short8*>(&Ks[(nf * 16 + l15) * LDT + 32 + l4 * 8]);
      accs[nf] = __builtin_amdgcn_mfma_f32_16x16x32_bf16(qf[0], kf0, accs[nf], 0, 0, 0);
      accs[nf] = __builtin_amdgcn_mfma_f32_16x16x32_bf16(qf[1], kf1, accs[nf], 0, 0, 0);
    }
    __builtin_amdgcn_s_setprio(0);

    // online softmax (16-lane shfl reductions); mask only on diagonal tile
    float p[4][4], tm[4];
    const int qrow_base = q0 + wave * 16 + l4 * 4;
#pragma unroll
    for (int r = 0; r < 4; ++r) tm[r] = -INFINITY;
    if (t == qt) {
#pragma unroll
      for (int nf = 0; nf < 4; ++nf) {
        int kv = kv0 + nf * 16 + l15;
#pragma unroll
        for (int r = 0; r < 4; ++r) {
          float v = accs[nf][r];
          if (kv > qrow_base + r) v = -INFINITY;
          p[nf][r] = v;
          tm[r] = fmaxf(tm[r], v);
        }
      }
    } else {
#pragma unroll
      for (int nf = 0; nf < 4; ++nf)
#pragma unroll
        for (int r = 0; r < 4; ++r) {
          float v = accs[nf][r];
          p[nf][r] = v;
          tm[r] = fmaxf(tm[r], v);
        }
    }
#pragma unroll
    for (int mset = 1; mset < 16; mset <<= 1)
#pragma unroll
      for (int r = 0; r < 4; ++r)
        tm[r] = fmaxf(tm[r], __shfl_xor(tm[r], mset));
    float corr[4], ts[4];
#pragma unroll
    for (int r = 0; r < 4; ++r) {
      float mn = fmaxf(m_run[r], tm[r]);
      corr[r] = __expf(m_run[r] - mn);
      m_run[r] = mn;
      ts[r] = 0.f;
    }
#pragma unroll
    for (int nf = 0; nf < 4; ++nf)
#pragma unroll
      for (int r = 0; r < 4; ++r) {
        float e = __expf(p[nf][r] - m_run[r]);
        p[nf][r] = e;
        ts[r] += e;
      }
#pragma unroll
    for (int mset = 1; mset < 16; mset <<= 1)
#pragma unroll
      for (int r = 0; r < 4; ++r)
        ts[r] += __shfl_xor(ts[r], mset);
#pragma unroll
    for (int r = 0; r < 4; ++r) l_run[r] = l_run[r] * corr[r] + ts[r];
#pragma unroll
    for (int nf = 0; nf < 4; ++nf)
#pragma unroll
      for (int r = 0; r < 4; ++r)
        o[nf][r] *= corr[r];

    // P -> LDS (C-layout scatter). Ps rows are WAVE-PRIVATE (wave w writes
    // and reads only rows [16w,16w+16)) -> no __syncthreads needed; the
    // compiler's lgkmcnt covers within-wave write->read ordering.
#pragma unroll
    for (int nf = 0; nf < 4; ++nf)
#pragma unroll
      for (int r = 0; r < 4; ++r)
        Ps[(wave * 16 + l4 * 4 + r) * LDT + nf * 16 + l15] = f2bf(p[nf][r]);

    // O += P V
    __builtin_amdgcn_s_setprio(1);
#pragma unroll
    for (int c = 0; c < 2; ++c) {
      short8 pa = *reinterpret_cast<const short8*>(&Ps[(wave * 16 + l15) * LDT + c * 32 + l4 * 8]);
#pragma unroll
      for (int nf = 0; nf < 4; ++nf) {
        short8 vbf = *reinterpret_cast<const short8*>(&Vt[(nf * 16 + l15) * LDT + c * 32 + l4 * 8]);
        o[nf] = __builtin_amdgcn_mfma_f32_16x16x32_bf16(pa, vbf, o[nf], 0, 0, 0);
      }
    }
    __builtin_amdgcn_s_setprio(0);
  }

  // epilogue: O /= l, write bf16 ctx
#pragma unroll
  for (int r = 0; r < 4; ++r) {
    float inv = 1.f / l_run[r];
    const int q = q0 + wave * 16 + l4 * 4 + r;
    unsigned short* op = ctx + (bbase + q) * D_MODEL + h * HEAD_D;
#pragma unroll
    for (int nf = 0; nf < 4; ++nf)
      op[nf * 16 + l15] = f2bf(o[nf][r] * inv);
  }
}

// ---------------- launch ----------------
extern "C" void kernel_launch(void* const* d_in, const int* in_sizes, int n_in,
                              void* d_out, int out_size, void* d_ws, size_t ws_size,
                              hipStream_t stream) {
  const float* x     = (const float*)d_in[0];
  const float* w_qkv = (const float*)d_in[1];
  const float* w_out = (const float*)d_in[2];
  float* out = (float*)d_out;

  char* p = (char*)d_ws;
  unsigned short* xb    = (unsigned short*)p; p += (size_t)4096 * 1024 * 2;
  unsigned short* wqkvT = (unsigned short*)p; p += (size_t)3072 * 1024 * 2;
  unsigned short* woutT = (unsigned short*)p; p += (size_t)1024 * 1024 * 2;
  unsigned short* qkv   = (unsigned short*)p; p += (size_t)4096 * 3072 * 2;
  unsigned short* ctx   = (unsigned short*)p; p += (size_t)4096 * 1024 * 2;

  cast_f32_bf16<<<4096, 256, 0, stream>>>(x, xb, 4096 * 1024 / 4);
  transpose_cast<<<dim3(3072 / 32, 1024 / 32), dim3(32, 8), 0, stream>>>(w_qkv, wqkvT, 1024, 3072);
  transpose_cast<<<dim3(1024 / 32, 1024 / 32), dim3(32, 8), 0, stream>>>(w_out, woutT, 1024, 1024);
  gemm_bt<unsigned short><<<dim3(3072 / 128, 4096 / 128), 256, 0, stream>>>(xb, wqkvT, qkv, 4096, 3072, 1024);
  attn_kernel<<<dim3(S_LEN / 64, BATCH * N_HEADS), 256, 0, stream>>>(qkv, ctx);
  gemm_bt<float><<<dim3(1024 / 128, 4096 / 128), 256, 0, stream>>>(ctx, woutT, out, 4096, 1024, 1024);
}

// Round 10
// 213.853 us; speedup vs baseline: 1.3369x; 1.2475x over previous
//
#include <hip/hip_runtime.h>
#include <hip/hip_bf16.h>
#include <stdint.h>
#include <cmath>

typedef __attribute__((ext_vector_type(8))) short short8;
typedef __attribute__((ext_vector_type(4))) float f32x4;

#define D_MODEL 1024
#define S_LEN   2048
#define N_HEADS 16
#define HEAD_D  64
#define BATCH   2
#define NROWS   (BATCH * S_LEN)          // 4096
#define MLSTRIDE (NROWS * N_HEADS)       // 65536

__device__ __forceinline__ unsigned short f2bf(float f) {
  __hip_bfloat16 h = __float2bfloat16(f);
  return *reinterpret_cast<unsigned short*>(&h);
}

__device__ __forceinline__ float bf2f(unsigned short u) {
  unsigned int b = ((unsigned int)u) << 16;
  return *reinterpret_cast<float*>(&b);
}

__device__ __forceinline__ unsigned int pack2(unsigned short lo, unsigned short hi) {
  return (unsigned int)lo | ((unsigned int)hi << 16);
}

// async global->LDS, 16B per lane. LDS base must be wave-uniform; HW adds lane*16.
__device__ __forceinline__ void gload_lds16(const void* g, void* l) {
  auto gp = (const __attribute__((address_space(1))) unsigned int*)(uintptr_t)g;
  auto lp = (__attribute__((address_space(3))) unsigned int*)(unsigned int)(uintptr_t)l;
  __builtin_amdgcn_global_load_lds(gp, lp, 16, 0, 0);
}

// ---------------- cast fp32 -> bf16 (vectorized) ----------------
__global__ void cast_f32_bf16(const float* __restrict__ in, unsigned short* __restrict__ out, int n4) {
  int i = blockIdx.x * blockDim.x + threadIdx.x;
  if (i >= n4) return;
  float4 v = reinterpret_cast<const float4*>(in)[i];
  ushort4 o;
  o.x = f2bf(v.x); o.y = f2bf(v.y); o.z = f2bf(v.z); o.w = f2bf(v.w);
  reinterpret_cast<ushort4*>(out)[i] = o;
}

// ---------------- transpose + cast: out[C][R] = bf16(in[R][C]) ----------------
__global__ void transpose_cast(const float* __restrict__ in, unsigned short* __restrict__ out, int R, int C) {
  __shared__ float tile[32][33];
  int c0 = blockIdx.x * 32, r0 = blockIdx.y * 32;
  int tx = threadIdx.x, ty = threadIdx.y;  // blockDim (32,8)
#pragma unroll
  for (int j = 0; j < 32; j += 8)
    tile[ty + j][tx] = in[(size_t)(r0 + ty + j) * C + c0 + tx];
  __syncthreads();
#pragma unroll
  for (int j = 0; j < 32; j += 8)
    out[(size_t)(c0 + ty + j) * R + r0 + tx] = f2bf(tile[tx][ty + j]);
}

// ---------------- bf16 GEMM, C = A * BT^T   (A[M,K], BT[N,K]) ----------------
template <typename OutT>
__global__ __launch_bounds__(256) void gemm_bt(
    const unsigned short* __restrict__ A,
    const unsigned short* __restrict__ BT,
    OutT* __restrict__ C,
    int M, int N, int K)
{
  constexpr int BK = 32;
  __shared__ unsigned short As[128 * BK];
  __shared__ unsigned short Bs[128 * BK];
  const int tid = threadIdx.x;
  const int wave = tid >> 6, lane = tid & 63;
  const int l15 = lane & 15, l4 = lane >> 4;
  const int wr = wave >> 1, wc = wave & 1;
  const size_t m0 = (size_t)blockIdx.y * 128, n0 = (size_t)blockIdx.x * 128;

  f32x4 acc[4][4];
#pragma unroll
  for (int m = 0; m < 4; ++m)
#pragma unroll
    for (int n = 0; n < 4; ++n) acc[m][n] = 0.f;

  for (int k0 = 0; k0 < K; k0 += BK) {
    __syncthreads();
#pragma unroll
    for (int it = 0; it < 2; ++it) {
      const int base = it * 256 + wave * 64;         // wave-uniform chunk base
      const int chunk = base + lane;                  // per-lane chunk
      const int row = chunk >> 2, k8 = (chunk & 3) * 8;
      gload_lds16(A + (m0 + row) * K + k0 + k8, &As[base * 8]);
      gload_lds16(BT + (n0 + row) * K + k0 + k8, &Bs[base * 8]);
    }
    __syncthreads();
    short8 af[4], bfr[4];
#pragma unroll
    for (int m = 0; m < 4; ++m)
      af[m] = *reinterpret_cast<const short8*>(&As[(wr * 64 + m * 16 + l15) * BK + l4 * 8]);
#pragma unroll
    for (int n = 0; n < 4; ++n)
      bfr[n] = *reinterpret_cast<const short8*>(&Bs[(wc * 64 + n * 16 + l15) * BK + l4 * 8]);
#pragma unroll
    for (int m = 0; m < 4; ++m)
#pragma unroll
      for (int n = 0; n < 4; ++n)
        acc[m][n] = __builtin_amdgcn_mfma_f32_16x16x32_bf16(af[m], bfr[n], acc[m][n], 0, 0, 0);
  }

  // C layout: col = lane&15, row = (lane>>4)*4 + reg   [m89-verified]
#pragma unroll
  for (int m = 0; m < 4; ++m)
#pragma unroll
    for (int n = 0; n < 4; ++n)
#pragma unroll
      for (int r = 0; r < 4; ++r) {
        size_t row = m0 + wr * 64 + m * 16 + l4 * 4 + r;
        size_t col = n0 + wc * 64 + n * 16 + l15;
        if constexpr (sizeof(OutT) == 2)
          C[row * N + col] = (OutT)f2bf(acc[m][n][r]);
        else
          C[row * N + col] = acc[m][n][r];
      }
}

// ---------------- causal flash attention, 2-way KV-split ----------------
// grid: (32, B*H, 2). block: 256 (4 waves), each wave owns 16 q rows.
// Split z covers KV tiles [t_lo,t_hi): split0=[0,n0), split1=[n0,nt),
// n0=(nt+1)/2 -> max serial depth 16 (was 32). Partials UNNORMALIZED:
// o -> ctx (split0) / part1 (split1), (m,l) -> ml[]. attn_combine merges.
// T13 defer-max: wave-wide __all(tm<=m+8) skips max-tree + rescale (no
// shfl tree on the common path); l accumulated as per-lane partials,
// tree'd once at block end.
__global__ __launch_bounds__(256) void attn_kernel(
    const unsigned short* __restrict__ qkv,  // [B*S, 3*D] bf16
    unsigned short* __restrict__ ctx,        // split0 partial o (unnorm)
    unsigned short* __restrict__ part1,      // split1 partial o (unnorm)
    float2* __restrict__ ml)                 // [2][NROWS][H] (m,l)
{
  constexpr int LDT = 72;  // padded row; rows stay 16B-aligned (144B)
  __shared__ unsigned short Ks[64 * LDT];
  __shared__ unsigned short Vt[64 * LDT];   // transposed: Vt[d][kv]
  __shared__ unsigned short Ps[64 * LDT];

  const int tid = threadIdx.x;
  const int wave = tid >> 6, lane = tid & 63;
  const int l15 = lane & 15, l4 = lane >> 4;
  const int bh = blockIdx.y;
  const int spl = blockIdx.z;
  const int qt = ((31 - (int)blockIdx.x) + ((bh >> 3) << 3)) & 31;  // CU-balance swizzle
  const int b = bh >> 4, h = bh & 15;
  const int q0 = qt * 64;
  const int nt = qt + 1;
  const int n0 = (nt + 1) >> 1;
  const int t_lo = spl ? n0 : 0;
  const int t_hi = spl ? nt : n0;
  if (t_lo >= t_hi) return;   // empty split (qt==0, spl==1); uniform per block

  const size_t rowstride = 3 * D_MODEL;
  const size_t bbase = (size_t)b * S_LEN;

  // Q fragments in registers for the whole loop, pre-scaled by 1/8 (exact).
  short8 qf[2];
  {
    const int qrow = q0 + wave * 16 + l15;
    const unsigned short* qp = qkv + (bbase + qrow) * rowstride + h * HEAD_D;
    qf[0] = *reinterpret_cast<const short8*>(qp + l4 * 8);
    qf[1] = *reinterpret_cast<const short8*>(qp + 32 + l4 * 8);
#pragma unroll
    for (int j = 0; j < 8; ++j) {
      qf[0][j] = (short)f2bf(bf2f((unsigned short)qf[0][j]) * 0.125f);
      qf[1][j] = (short)f2bf(bf2f((unsigned short)qf[1][j]) * 0.125f);
    }
  }

  f32x4 o[4];
#pragma unroll
  for (int nf = 0; nf < 4; ++nf) o[nf] = 0.f;
  float m_run[4], l_run[4];
#pragma unroll
  for (int r = 0; r < 4; ++r) { m_run[r] = -INFINITY; l_run[r] = 0.f; }

  // K staging indices: row sr_k = tid>>2, cols sck..sck+15
  const int sr_k = tid >> 2;
  const int sck  = (tid & 3) * 16;
  // V staging indices: rows kvr, kvr+1, cols a8..a8+7
  const int kvr = (tid >> 3) * 2;
  const int a8  = (tid & 7) * 8;

  const unsigned short* kbase = qkv + bbase * rowstride + h * HEAD_D + D_MODEL;
  const unsigned short* vbase = qkv + bbase * rowstride + h * HEAD_D + 2 * D_MODEL;

  // prologue: load tile t_lo K/V into registers
  short8 kr0, kr1, vr0, vr1;
  {
    const unsigned short* kp = kbase + (size_t)(t_lo * 64 + sr_k) * rowstride + sck;
    const unsigned short* vp = vbase + (size_t)(t_lo * 64 + kvr) * rowstride + a8;
    kr0 = *reinterpret_cast<const short8*>(kp);
    kr1 = *reinterpret_cast<const short8*>(kp + 8);
    vr0 = *reinterpret_cast<const short8*>(vp);
    vr1 = *reinterpret_cast<const short8*>(vp + rowstride);
  }

  for (int t = t_lo; t < t_hi; ++t) {
    const int kv0 = t * 64;
    __syncthreads();  // prev tile's consumers done with Ks/Vt

    // write staged registers -> LDS
    *reinterpret_cast<short8*>(&Ks[sr_k * LDT + sck])     = kr0;
    *reinterpret_cast<short8*>(&Ks[sr_k * LDT + sck + 8]) = kr1;
#pragma unroll
    for (int j = 0; j < 8; ++j)
      *reinterpret_cast<unsigned int*>(&Vt[(a8 + j) * LDT + kvr]) =
          pack2((unsigned short)vr0[j], (unsigned short)vr1[j]);

    // issue next tile's loads (fly during compute below)
    if (t + 1 < t_hi) {
      const unsigned short* kp = kbase + (size_t)(kv0 + 64 + sr_k) * rowstride + sck;
      const unsigned short* vp = vbase + (size_t)(kv0 + 64 + kvr) * rowstride + a8;
      kr0 = *reinterpret_cast<const short8*>(kp);
      kr1 = *reinterpret_cast<const short8*>(kp + 8);
      vr0 = *reinterpret_cast<const short8*>(vp);
      vr1 = *reinterpret_cast<const short8*>(vp + rowstride);
    }
    __syncthreads();

    // S = Q K^T : 16(q) x 64(kv), B-frag from Ks rows
    f32x4 accs[4];
#pragma unroll
    for (int nf = 0; nf < 4; ++nf) accs[nf] = 0.f;
    __builtin_amdgcn_s_setprio(1);
#pragma unroll
    for (int nf = 0; nf < 4; ++nf) {
      short8 kf0 = *reinterpret_cast<const short8*>(&Ks[(nf * 16 + l15) * LDT + l4 * 8]);
      short8 kf1 = *reinterpret_cast<const short8*>(&Ks[(nf * 16 + l15) * LDT + 32 + l4 * 8]);
      accs[nf] = __builtin_amdgcn_mfma_f32_16x16x32_bf16(qf[0], kf0, accs[nf], 0, 0, 0);
      accs[nf] = __builtin_amdgcn_mfma_f32_16x16x32_bf16(qf[1], kf1, accs[nf], 0, 0, 0);
    }
    __builtin_amdgcn_s_setprio(0);

    // per-lane tile max (mask only on diagonal tile)
    float p[4][4], tm[4];
#pragma unroll
    for (int r = 0; r < 4; ++r) tm[r] = -INFINITY;
    if (t == qt) {
      const int qrow_base = q0 + wave * 16 + l4 * 4;
#pragma unroll
      for (int nf = 0; nf < 4; ++nf) {
        int kv = kv0 + nf * 16 + l15;
#pragma unroll
        for (int r = 0; r < 4; ++r) {
          float v = accs[nf][r];
          if (kv > qrow_base + r) v = -INFINITY;
          p[nf][r] = v;
          tm[r] = fmaxf(tm[r], v);
        }
      }
    } else {
#pragma unroll
      for (int nf = 0; nf < 4; ++nf)
#pragma unroll
        for (int r = 0; r < 4; ++r) {
          float v = accs[nf][r];
          p[nf][r] = v;
          tm[r] = fmaxf(tm[r], v);
        }
    }

    // T13 defer-max: skip max-tree + rescale when safe (common case)
    int fastf = 1;
#pragma unroll
    for (int r = 0; r < 4; ++r)
      fastf &= (tm[r] <= m_run[r] + 8.f) ? 1 : 0;
    if (!__all(fastf)) {
#pragma unroll
      for (int mset = 1; mset < 16; mset <<= 1)
#pragma unroll
        for (int r = 0; r < 4; ++r)
          tm[r] = fmaxf(tm[r], __shfl_xor(tm[r], mset));
      float corr[4];
#pragma unroll
      for (int r = 0; r < 4; ++r) {
        float mn = fmaxf(m_run[r], tm[r]);
        corr[r] = __expf(m_run[r] - mn);
        m_run[r] = mn;
        l_run[r] *= corr[r];
      }
#pragma unroll
      for (int nf = 0; nf < 4; ++nf)
#pragma unroll
        for (int r = 0; r < 4; ++r)
          o[nf][r] *= corr[r];
    }

    // exp + per-lane l accumulation (no per-tile sum tree)
#pragma unroll
    for (int nf = 0; nf < 4; ++nf)
#pragma unroll
      for (int r = 0; r < 4; ++r)
        p[nf][r] = __expf(p[nf][r] - m_run[r]);
#pragma unroll
    for (int r = 0; r < 4; ++r)
      l_run[r] += p[0][r] + p[1][r] + p[2][r] + p[3][r];

    // P -> LDS (C-layout scatter). Ps rows are WAVE-PRIVATE -> no barrier.
#pragma unroll
    for (int nf = 0; nf < 4; ++nf)
#pragma unroll
      for (int r = 0; r < 4; ++r)
        Ps[(wave * 16 + l4 * 4 + r) * LDT + nf * 16 + l15] = f2bf(p[nf][r]);

    // O += P V
    __builtin_amdgcn_s_setprio(1);
#pragma unroll
    for (int c = 0; c < 2; ++c) {
      short8 pa = *reinterpret_cast<const short8*>(&Ps[(wave * 16 + l15) * LDT + c * 32 + l4 * 8]);
#pragma unroll
      for (int nf = 0; nf < 4; ++nf) {
        short8 vbf = *reinterpret_cast<const short8*>(&Vt[(nf * 16 + l15) * LDT + c * 32 + l4 * 8]);
        o[nf] = __builtin_amdgcn_mfma_f32_16x16x32_bf16(pa, vbf, o[nf], 0, 0, 0);
      }
    }
    __builtin_amdgcn_s_setprio(0);
  }

  // final l reduction across the 16-lane row group (once per block)
#pragma unroll
  for (int mset = 1; mset < 16; mset <<= 1)
#pragma unroll
    for (int r = 0; r < 4; ++r)
      l_run[r] += __shfl_xor(l_run[r], mset);

  // epilogue: write UNNORMALIZED o + (m,l)
  unsigned short* dst = spl ? part1 : ctx;
#pragma unroll
  for (int r = 0; r < 4; ++r) {
    const int q = q0 + wave * 16 + l4 * 4 + r;
    unsigned short* op = dst + (bbase + q) * D_MODEL + h * HEAD_D;
#pragma unroll
    for (int nf = 0; nf < 4; ++nf)
      op[nf * 16 + l15] = f2bf(o[nf][r]);
  }
  if (l15 == 0) {
#pragma unroll
    for (int r = 0; r < 4; ++r) {
      const int q = q0 + wave * 16 + l4 * 4 + r;
      float2 v; v.x = m_run[r]; v.y = l_run[r];
      ml[spl * MLSTRIDE + ((int)bbase + q) * N_HEADS + h] = v;
    }
  }
}

// ---------------- combine the two KV-splits ----------------
// out = (o0*e^{m0-M} + o1*e^{m1-M}) / (l0*e^{m0-M} + l1*e^{m1-M});
// in-place on ctx (each thread reads its 8 elems before writing).
__global__ __launch_bounds__(256) void attn_combine(
    const unsigned short* __restrict__ o1,
    const float2* __restrict__ ml,
    unsigned short* __restrict__ ctx)
{
  const int tid = threadIdx.x;
  const int pi = blockIdx.x * 32 + (tid >> 3);   // (row,head) pair
  const int lane8 = tid & 7;
  const int r = pi >> 4, h = pi & 15;
  const int s = r & (S_LEN - 1);
  const int qt = s >> 6;
  const size_t off = (size_t)r * D_MODEL + h * HEAD_D + lane8 * 8;
  short8 a = *reinterpret_cast<const short8*>(&ctx[off]);
  float2 ml0 = ml[r * N_HEADS + h];
  short8 outv;
  if (qt == 0) {
    float inv = 1.f / ml0.y;
#pragma unroll
    for (int j = 0; j < 8; ++j) outv[j] = (short)f2bf(bf2f((unsigned short)a[j]) * inv);
  } else {
    short8 bv = *reinterpret_cast<const short8*>(&o1[off]);
    float2 ml1 = ml[MLSTRIDE + r * N_HEADS + h];
    float M = fmaxf(ml0.x, ml1.x);
    float w0 = __expf(ml0.x - M), w1 = __expf(ml1.x - M);
    float inv = 1.f / (w0 * ml0.y + w1 * ml1.y);
#pragma unroll
    for (int j = 0; j < 8; ++j)
      outv[j] = (short)f2bf((bf2f((unsigned short)a[j]) * w0 + bf2f((unsigned short)bv[j]) * w1) * inv);
  }
  *reinterpret_cast<short8*>(&ctx[off]) = outv;
}

// ---------------- launch ----------------
extern "C" void kernel_launch(void* const* d_in, const int* in_sizes, int n_in,
                              void* d_out, int out_size, void* d_ws, size_t ws_size,
                              hipStream_t stream) {
  const float* x     = (const float*)d_in[0];
  const float* w_qkv = (const float*)d_in[1];
  const float* w_out = (const float*)d_in[2];
  float* out = (float*)d_out;

  char* p = (char*)d_ws;
  unsigned short* xb    = (unsigned short*)p; p += (size_t)4096 * 1024 * 2;  // dead after qkv GEMM -> part1
  unsigned short* wqkvT = (unsigned short*)p; p += (size_t)3072 * 1024 * 2;  // dead after qkv GEMM -> ml
  unsigned short* woutT = (unsigned short*)p; p += (size_t)1024 * 1024 * 2;
  unsigned short* qkv   = (unsigned short*)p; p += (size_t)4096 * 3072 * 2;
  unsigned short* ctx   = (unsigned short*)p; p += (size_t)4096 * 1024 * 2;

  unsigned short* part1 = xb;                  // 8.4 MB, fits exactly
  float2*         ml    = (float2*)wqkvT;      // 1 MB, fits

  cast_f32_bf16<<<4096, 256, 0, stream>>>(x, xb, 4096 * 1024 / 4);
  transpose_cast<<<dim3(3072 / 32, 1024 / 32), dim3(32, 8), 0, stream>>>(w_qkv, wqkvT, 1024, 3072);
  transpose_cast<<<dim3(1024 / 32, 1024 / 32), dim3(32, 8), 0, stream>>>(w_out, woutT, 1024, 1024);
  gemm_bt<unsigned short><<<dim3(3072 / 128, 4096 / 128), 256, 0, stream>>>(xb, wqkvT, qkv, 4096, 3072, 1024);
  attn_kernel<<<dim3(S_LEN / 64, BATCH * N_HEADS, 2), 256, 0, stream>>>(qkv, ctx, part1, ml);
  attn_combine<<<(NROWS * N_HEADS) / 32, 256, 0, stream>>>(part1, ml, ctx);
  gemm_bt<float><<<dim3(1024 / 128, 4096 / 128), 256, 0, stream>>>(ctx, woutT, out, 4096, 1024, 1024);
}

// Round 12
// 208.001 us; speedup vs baseline: 1.3745x; 1.0281x over previous
//
#include <hip/hip_runtime.h>
#include <hip/hip_bf16.h>
#include <stdint.h>
#include <cmath>

typedef __attribute__((ext_vector_type(8))) short short8;
typedef __attribute__((ext_vector_type(4))) float f32x4;

#define D_MODEL 1024
#define S_LEN   2048
#define N_HEADS 16
#define HEAD_D  64
#define BATCH   2
#define NROWS   (BATCH * S_LEN)          // 4096
#define MLSTRIDE (NROWS * N_HEADS)       // 65536

__device__ __forceinline__ unsigned short f2bf(float f) {
  __hip_bfloat16 h = __float2bfloat16(f);
  return *reinterpret_cast<unsigned short*>(&h);
}

__device__ __forceinline__ float bf2f(unsigned short u) {
  unsigned int b = ((unsigned int)u) << 16;
  return *reinterpret_cast<float*>(&b);
}

__device__ __forceinline__ unsigned int pack2(unsigned short lo, unsigned short hi) {
  return (unsigned int)lo | ((unsigned int)hi << 16);
}

// async global->LDS, 16B per lane. LDS base must be wave-uniform; HW adds lane*16.
__device__ __forceinline__ void gload_lds16(const void* g, void* l) {
  auto gp = (const __attribute__((address_space(1))) unsigned int*)(uintptr_t)g;
  auto lp = (__attribute__((address_space(3))) unsigned int*)(unsigned int)(uintptr_t)l;
  __builtin_amdgcn_global_load_lds(gp, lp, 16, 0, 0);
}

// ---------------- cast fp32 -> bf16 (vectorized) ----------------
__global__ void cast_f32_bf16(const float* __restrict__ in, unsigned short* __restrict__ out, int n4) {
  int i = blockIdx.x * blockDim.x + threadIdx.x;
  if (i >= n4) return;
  float4 v = reinterpret_cast<const float4*>(in)[i];
  ushort4 o;
  o.x = f2bf(v.x); o.y = f2bf(v.y); o.z = f2bf(v.z); o.w = f2bf(v.w);
  reinterpret_cast<ushort4*>(out)[i] = o;
}

// ---------------- transpose + cast: out[C][R] = bf16(in[R][C]) ----------------
__global__ void transpose_cast(const float* __restrict__ in, unsigned short* __restrict__ out, int R, int C) {
  __shared__ float tile[32][33];
  int c0 = blockIdx.x * 32, r0 = blockIdx.y * 32;
  int tx = threadIdx.x, ty = threadIdx.y;  // blockDim (32,8)
#pragma unroll
  for (int j = 0; j < 32; j += 8)
    tile[ty + j][tx] = in[(size_t)(r0 + ty + j) * C + c0 + tx];
  __syncthreads();
#pragma unroll
  for (int j = 0; j < 32; j += 8)
    out[(size_t)(c0 + ty + j) * R + r0 + tx] = f2bf(tile[tx][ty + j]);
}

// ---------------- bf16 GEMM 128x128, C = A * BT^T ----------------
template <typename OutT>
__global__ __launch_bounds__(256) void gemm_bt(
    const unsigned short* __restrict__ A,
    const unsigned short* __restrict__ BT,
    OutT* __restrict__ C,
    int M, int N, int K)
{
  constexpr int BK = 32;
  __shared__ unsigned short As[128 * BK];
  __shared__ unsigned short Bs[128 * BK];
  const int tid = threadIdx.x;
  const int wave = tid >> 6, lane = tid & 63;
  const int l15 = lane & 15, l4 = lane >> 4;
  const int wr = wave >> 1, wc = wave & 1;
  const size_t m0 = (size_t)blockIdx.y * 128, n0 = (size_t)blockIdx.x * 128;

  f32x4 acc[4][4];
#pragma unroll
  for (int m = 0; m < 4; ++m)
#pragma unroll
    for (int n = 0; n < 4; ++n) acc[m][n] = 0.f;

  for (int k0 = 0; k0 < K; k0 += BK) {
    __syncthreads();
#pragma unroll
    for (int it = 0; it < 2; ++it) {
      const int base = it * 256 + wave * 64;         // wave-uniform chunk base
      const int chunk = base + lane;                  // per-lane chunk
      const int row = chunk >> 2, k8 = (chunk & 3) * 8;
      gload_lds16(A + (m0 + row) * K + k0 + k8, &As[base * 8]);
      gload_lds16(BT + (n0 + row) * K + k0 + k8, &Bs[base * 8]);
    }
    __syncthreads();
    short8 af[4], bfr[4];
#pragma unroll
    for (int m = 0; m < 4; ++m)
      af[m] = *reinterpret_cast<const short8*>(&As[(wr * 64 + m * 16 + l15) * BK + l4 * 8]);
#pragma unroll
    for (int n = 0; n < 4; ++n)
      bfr[n] = *reinterpret_cast<const short8*>(&Bs[(wc * 64 + n * 16 + l15) * BK + l4 * 8]);
#pragma unroll
    for (int m = 0; m < 4; ++m)
#pragma unroll
      for (int n = 0; n < 4; ++n)
        acc[m][n] = __builtin_amdgcn_mfma_f32_16x16x32_bf16(af[m], bfr[n], acc[m][n], 0, 0, 0);
  }

  // C layout: col = lane&15, row = (lane>>4)*4 + reg   [m89-verified]
#pragma unroll
  for (int m = 0; m < 4; ++m)
#pragma unroll
    for (int n = 0; n < 4; ++n)
#pragma unroll
      for (int r = 0; r < 4; ++r) {
        size_t row = m0 + wr * 64 + m * 16 + l4 * 4 + r;
        size_t col = n0 + wc * 64 + n * 16 + l15;
        if constexpr (sizeof(OutT) == 2)
          C[row * N + col] = (OutT)f2bf(acc[m][n][r]);
        else
          C[row * N + col] = acc[m][n][r];
      }
}

// ---------------- bf16 GEMM 64x128 (occupancy variant for small-N) ----------------
// grid (N/128, M/64): doubles block count vs 128x128 for N=1024 -> 2 blocks/CU.
__global__ __launch_bounds__(256) void gemm_bt64(
    const unsigned short* __restrict__ A,
    const unsigned short* __restrict__ BT,
    float* __restrict__ C,
    int M, int N, int K)
{
  constexpr int BK = 32;
  __shared__ unsigned short As[64 * BK];
  __shared__ unsigned short Bs[128 * BK];
  const int tid = threadIdx.x;
  const int wave = tid >> 6, lane = tid & 63;
  const int l15 = lane & 15, l4 = lane >> 4;
  const int wr = wave >> 1, wc = wave & 1;   // 2x2 wave grid; wave tile 32x64
  const size_t m0 = (size_t)blockIdx.y * 64, n0 = (size_t)blockIdx.x * 128;

  f32x4 acc[2][4];
#pragma unroll
  for (int m = 0; m < 2; ++m)
#pragma unroll
    for (int n = 0; n < 4; ++n) acc[m][n] = 0.f;

  for (int k0 = 0; k0 < K; k0 += BK) {
    __syncthreads();
    {
      // A: 64x32 = 256 chunks, one per thread
      const int base = wave * 64;
      const int chunk = base + lane;
      const int row = chunk >> 2, k8 = (chunk & 3) * 8;
      gload_lds16(A + (m0 + row) * K + k0 + k8, &As[base * 8]);
    }
#pragma unroll
    for (int it = 0; it < 2; ++it) {
      // B: 128x32 = 512 chunks
      const int base = it * 256 + wave * 64;
      const int chunk = base + lane;
      const int row = chunk >> 2, k8 = (chunk & 3) * 8;
      gload_lds16(BT + (n0 + row) * K + k0 + k8, &Bs[base * 8]);
    }
    __syncthreads();
    short8 af[2], bfr[4];
#pragma unroll
    for (int m = 0; m < 2; ++m)
      af[m] = *reinterpret_cast<const short8*>(&As[(wr * 32 + m * 16 + l15) * BK + l4 * 8]);
#pragma unroll
    for (int n = 0; n < 4; ++n)
      bfr[n] = *reinterpret_cast<const short8*>(&Bs[(wc * 64 + n * 16 + l15) * BK + l4 * 8]);
#pragma unroll
    for (int m = 0; m < 2; ++m)
#pragma unroll
      for (int n = 0; n < 4; ++n)
        acc[m][n] = __builtin_amdgcn_mfma_f32_16x16x32_bf16(af[m], bfr[n], acc[m][n], 0, 0, 0);
  }

#pragma unroll
  for (int m = 0; m < 2; ++m)
#pragma unroll
    for (int n = 0; n < 4; ++n)
#pragma unroll
      for (int r = 0; r < 4; ++r) {
        size_t row = m0 + wr * 32 + m * 16 + l4 * 4 + r;
        size_t col = n0 + wc * 64 + n * 16 + l15;
        C[row * N + col] = acc[m][n][r];
      }
}

// ---------------- causal flash attention, 2-way KV-split ----------------
// grid: (32, B*H, 2). block: 256 (4 waves), each wave owns 16 q rows.
// LDS: Ks is REUSED for the P-scatter (Ks dead after QK^T reads; extra
// barrier guards cross-wave read->write). 2 buffers x 9216B = 18432B ->
// 8 blocks/CU (was 5 with a separate Ps). Split z covers KV tiles
// [t_lo,t_hi); partials unnormalized; attn_combine merges. T13 defer-max.
__global__ __launch_bounds__(256) void attn_kernel(
    const unsigned short* __restrict__ qkv,  // [B*S, 3*D] bf16
    unsigned short* __restrict__ ctx,        // split0 partial o (unnorm)
    unsigned short* __restrict__ part1,      // split1 partial o (unnorm)
    float2* __restrict__ ml)                 // [2][NROWS][H] (m,l)
{
  constexpr int LDT = 72;  // padded row; rows stay 16B-aligned (144B)
  __shared__ unsigned short Ks[64 * LDT];   // K tile, then P tile (overlaid)
  __shared__ unsigned short Vt[64 * LDT];   // transposed: Vt[d][kv]

  const int tid = threadIdx.x;
  const int wave = tid >> 6, lane = tid & 63;
  const int l15 = lane & 15, l4 = lane >> 4;
  const int bh = blockIdx.y;
  const int spl = blockIdx.z;
  const int qt = ((31 - (int)blockIdx.x) + ((bh >> 3) << 3)) & 31;  // CU-balance swizzle
  const int b = bh >> 4, h = bh & 15;
  const int q0 = qt * 64;
  const int nt = qt + 1;
  const int n0 = (nt + 1) >> 1;
  const int t_lo = spl ? n0 : 0;
  const int t_hi = spl ? nt : n0;
  if (t_lo >= t_hi) return;   // empty split (qt==0, spl==1); uniform per block

  const size_t rowstride = 3 * D_MODEL;
  const size_t bbase = (size_t)b * S_LEN;

  // Q fragments in registers for the whole loop, pre-scaled by 1/8 (exact).
  short8 qf[2];
  {
    const int qrow = q0 + wave * 16 + l15;
    const unsigned short* qp = qkv + (bbase + qrow) * rowstride + h * HEAD_D;
    qf[0] = *reinterpret_cast<const short8*>(qp + l4 * 8);
    qf[1] = *reinterpret_cast<const short8*>(qp + 32 + l4 * 8);
#pragma unroll
    for (int j = 0; j < 8; ++j) {
      qf[0][j] = (short)f2bf(bf2f((unsigned short)qf[0][j]) * 0.125f);
      qf[1][j] = (short)f2bf(bf2f((unsigned short)qf[1][j]) * 0.125f);
    }
  }

  f32x4 o[4];
#pragma unroll
  for (int nf = 0; nf < 4; ++nf) o[nf] = 0.f;
  float m_run[4], l_run[4];
#pragma unroll
  for (int r = 0; r < 4; ++r) { m_run[r] = -INFINITY; l_run[r] = 0.f; }

  // K staging indices: row sr_k = tid>>2, cols sck..sck+15
  const int sr_k = tid >> 2;
  const int sck  = (tid & 3) * 16;
  // V staging indices: rows kvr, kvr+1, cols a8..a8+7
  const int kvr = (tid >> 3) * 2;
  const int a8  = (tid & 7) * 8;

  const unsigned short* kbase = qkv + bbase * rowstride + h * HEAD_D + D_MODEL;
  const unsigned short* vbase = qkv + bbase * rowstride + h * HEAD_D + 2 * D_MODEL;

  // prologue: load tile t_lo K/V into registers
  short8 kr0, kr1, vr0, vr1;
  {
    const unsigned short* kp = kbase + (size_t)(t_lo * 64 + sr_k) * rowstride + sck;
    const unsigned short* vp = vbase + (size_t)(t_lo * 64 + kvr) * rowstride + a8;
    kr0 = *reinterpret_cast<const short8*>(kp);
    kr1 = *reinterpret_cast<const short8*>(kp + 8);
    vr0 = *reinterpret_cast<const short8*>(vp);
    vr1 = *reinterpret_cast<const short8*>(vp + rowstride);
  }

  for (int t = t_lo; t < t_hi; ++t) {
    const int kv0 = t * 64;
    __syncthreads();  // prev tile's consumers done with Ks(P)/Vt

    // write staged registers -> LDS
    *reinterpret_cast<short8*>(&Ks[sr_k * LDT + sck])     = kr0;
    *reinterpret_cast<short8*>(&Ks[sr_k * LDT + sck + 8]) = kr1;
#pragma unroll
    for (int j = 0; j < 8; ++j)
      *reinterpret_cast<unsigned int*>(&Vt[(a8 + j) * LDT + kvr]) =
          pack2((unsigned short)vr0[j], (unsigned short)vr1[j]);

    // issue next tile's loads (fly during compute below)
    if (t + 1 < t_hi) {
      const unsigned short* kp = kbase + (size_t)(kv0 + 64 + sr_k) * rowstride + sck;
      const unsigned short* vp = vbase + (size_t)(kv0 + 64 + kvr) * rowstride + a8;
      kr0 = *reinterpret_cast<const short8*>(kp);
      kr1 = *reinterpret_cast<const short8*>(kp + 8);
      vr0 = *reinterpret_cast<const short8*>(vp);
      vr1 = *reinterpret_cast<const short8*>(vp + rowstride);
    }
    __syncthreads();

    // S = Q K^T : 16(q) x 64(kv), B-frag from Ks rows
    f32x4 accs[4];
#pragma unroll
    for (int nf = 0; nf < 4; ++nf) accs[nf] = 0.f;
    __builtin_amdgcn_s_setprio(1);
#pragma unroll
    for (int nf = 0; nf < 4; ++nf) {
      short8 kf0 = *reinterpret_cast<const short8*>(&Ks[(nf * 16 + l15) * LDT + l4 * 8]);
      short8 kf1 = *reinterpret_cast<const short8*>(&Ks[(nf * 16 + l15) * LDT + 32 + l4 * 8]);
      accs[nf] = __builtin_amdgcn_mfma_f32_16x16x32_bf16(qf[0], kf0, accs[nf], 0, 0, 0);
      accs[nf] = __builtin_amdgcn_mfma_f32_16x16x32_bf16(qf[1], kf1, accs[nf], 0, 0, 0);
    }
    __builtin_amdgcn_s_setprio(0);

    // per-lane tile max (mask only on diagonal tile)
    float p[4][4], tm[4];
#pragma unroll
    for (int r = 0; r < 4; ++r) tm[r] = -INFINITY;
    if (t == qt) {
      const int qrow_base = q0 + wave * 16 + l4 * 4;
#pragma unroll
      for (int nf = 0; nf < 4; ++nf) {
        int kv = kv0 + nf * 16 + l15;
#pragma unroll
        for (int r = 0; r < 4; ++r) {
          float v = accs[nf][r];
          if (kv > qrow_base + r) v = -INFINITY;
          p[nf][r] = v;
          tm[r] = fmaxf(tm[r], v);
        }
      }
    } else {
#pragma unroll
      for (int nf = 0; nf < 4; ++nf)
#pragma unroll
        for (int r = 0; r < 4; ++r) {
          float v = accs[nf][r];
          p[nf][r] = v;
          tm[r] = fmaxf(tm[r], v);
        }
    }

    // T13 defer-max: skip max-tree + rescale when safe (common case)
    int fastf = 1;
#pragma unroll
    for (int r = 0; r < 4; ++r)
      fastf &= (tm[r] <= m_run[r] + 8.f) ? 1 : 0;
    if (!__all(fastf)) {
#pragma unroll
      for (int mset = 1; mset < 16; mset <<= 1)
#pragma unroll
        for (int r = 0; r < 4; ++r)
          tm[r] = fmaxf(tm[r], __shfl_xor(tm[r], mset));
      float corr[4];
#pragma unroll
      for (int r = 0; r < 4; ++r) {
        float mn = fmaxf(m_run[r], tm[r]);
        corr[r] = __expf(m_run[r] - mn);
        m_run[r] = mn;
        l_run[r] *= corr[r];
      }
#pragma unroll
      for (int nf = 0; nf < 4; ++nf)
#pragma unroll
        for (int r = 0; r < 4; ++r)
          o[nf][r] *= corr[r];
    }

    // exp + per-lane l accumulation (no per-tile sum tree)
#pragma unroll
    for (int nf = 0; nf < 4; ++nf)
#pragma unroll
      for (int r = 0; r < 4; ++r)
        p[nf][r] = __expf(p[nf][r] - m_run[r]);
#pragma unroll
    for (int r = 0; r < 4; ++r)
      l_run[r] += p[0][r] + p[1][r] + p[2][r] + p[3][r];

    // All waves' QK^T reads of Ks are complete before P overwrites it.
    __syncthreads();

    // P -> LDS (C-layout scatter) into the Ks buffer (overlay).
#pragma unroll
    for (int nf = 0; nf < 4; ++nf)
#pragma unroll
      for (int r = 0; r < 4; ++r)
        Ks[(wave * 16 + l4 * 4 + r) * LDT + nf * 16 + l15] = f2bf(p[nf][r]);

    // O += P V  (P rows are wave-private; within-wave lgkmcnt orders write->read)
    __builtin_amdgcn_s_setprio(1);
#pragma unroll
    for (int c = 0; c < 2; ++c) {
      short8 pa = *reinterpret_cast<const short8*>(&Ks[(wave * 16 + l15) * LDT + c * 32 + l4 * 8]);
#pragma unroll
      for (int nf = 0; nf < 4; ++nf) {
        short8 vbf = *reinterpret_cast<const short8*>(&Vt[(nf * 16 + l15) * LDT + c * 32 + l4 * 8]);
        o[nf] = __builtin_amdgcn_mfma_f32_16x16x32_bf16(pa, vbf, o[nf], 0, 0, 0);
      }
    }
    __builtin_amdgcn_s_setprio(0);
  }

  // final l reduction across the 16-lane row group (once per block)
#pragma unroll
  for (int mset = 1; mset < 16; mset <<= 1)
#pragma unroll
    for (int r = 0; r < 4; ++r)
      l_run[r] += __shfl_xor(l_run[r], mset);

  // epilogue: write UNNORMALIZED o + (m,l)
  unsigned short* dst = spl ? part1 : ctx;
#pragma unroll
  for (int r = 0; r < 4; ++r) {
    const int q = q0 + wave * 16 + l4 * 4 + r;
    unsigned short* op = dst + (bbase + q) * D_MODEL + h * HEAD_D;
#pragma unroll
    for (int nf = 0; nf < 4; ++nf)
      op[nf * 16 + l15] = f2bf(o[nf][r]);
  }
  if (l15 == 0) {
#pragma unroll
    for (int r = 0; r < 4; ++r) {
      const int q = q0 + wave * 16 + l4 * 4 + r;
      float2 v; v.x = m_run[r]; v.y = l_run[r];
      ml[spl * MLSTRIDE + ((int)bbase + q) * N_HEADS + h] = v;
    }
  }
}

// ---------------- combine the two KV-splits ----------------
__global__ __launch_bounds__(256) void attn_combine(
    const unsigned short* __restrict__ o1,
    const float2* __restrict__ ml,
    unsigned short* __restrict__ ctx)
{
  const int tid = threadIdx.x;
  const int pi = blockIdx.x * 32 + (tid >> 3);   // (row,head) pair
  const int lane8 = tid & 7;
  const int r = pi >> 4, h = pi & 15;
  const int s = r & (S_LEN - 1);
  const int qt = s >> 6;
  const size_t off = (size_t)r * D_MODEL + h * HEAD_D + lane8 * 8;
  short8 a = *reinterpret_cast<const short8*>(&ctx[off]);
  float2 ml0 = ml[r * N_HEADS + h];
  short8 outv;
  if (qt == 0) {
    float inv = 1.f / ml0.y;
#pragma unroll
    for (int j = 0; j < 8; ++j) outv[j] = (short)f2bf(bf2f((unsigned short)a[j]) * inv);
  } else {
    short8 bv = *reinterpret_cast<const short8*>(&o1[off]);
    float2 ml1 = ml[MLSTRIDE + r * N_HEADS + h];
    float M = fmaxf(ml0.x, ml1.x);
    float w0 = __expf(ml0.x - M), w1 = __expf(ml1.x - M);
    float inv = 1.f / (w0 * ml0.y + w1 * ml1.y);
#pragma unroll
    for (int j = 0; j < 8; ++j)
      outv[j] = (short)f2bf((bf2f((unsigned short)a[j]) * w0 + bf2f((unsigned short)bv[j]) * w1) * inv);
  }
  *reinterpret_cast<short8*>(&ctx[off]) = outv;
}

// ---------------- launch ----------------
extern "C" void kernel_launch(void* const* d_in, const int* in_sizes, int n_in,
                              void* d_out, int out_size, void* d_ws, size_t ws_size,
                              hipStream_t stream) {
  const float* x     = (const float*)d_in[0];
  const float* w_qkv = (const float*)d_in[1];
  const float* w_out = (const float*)d_in[2];
  float* out = (float*)d_out;

  char* p = (char*)d_ws;
  unsigned short* xb    = (unsigned short*)p; p += (size_t)4096 * 1024 * 2;  // dead after qkv GEMM -> part1
  unsigned short* wqkvT = (unsigned short*)p; p += (size_t)3072 * 1024 * 2;  // dead after qkv GEMM -> ml
  unsigned short* woutT = (unsigned short*)p; p += (size_t)1024 * 1024 * 2;
  unsigned short* qkv   = (unsigned short*)p; p += (size_t)4096 * 3072 * 2;
  unsigned short* ctx   = (unsigned short*)p; p += (size_t)4096 * 1024 * 2;

  unsigned short* part1 = xb;                  // 8.4 MB, fits exactly
  float2*         ml    = (float2*)wqkvT;      // 1 MB, fits

  cast_f32_bf16<<<4096, 256, 0, stream>>>(x, xb, 4096 * 1024 / 4);
  transpose_cast<<<dim3(3072 / 32, 1024 / 32), dim3(32, 8), 0, stream>>>(w_qkv, wqkvT, 1024, 3072);
  transpose_cast<<<dim3(1024 / 32, 1024 / 32), dim3(32, 8), 0, stream>>>(w_out, woutT, 1024, 1024);
  gemm_bt<unsigned short><<<dim3(3072 / 128, 4096 / 128), 256, 0, stream>>>(xb, wqkvT, qkv, 4096, 3072, 1024);
  attn_kernel<<<dim3(S_LEN / 64, BATCH * N_HEADS, 2), 256, 0, stream>>>(qkv, ctx, part1, ml);
  attn_combine<<<(NROWS * N_HEADS) / 32, 256, 0, stream>>>(part1, ml, ctx);
  gemm_bt64<<<dim3(1024 / 128, 4096 / 64), 256, 0, stream>>>(ctx, woutT, out, 4096, 1024, 1024);
}

// Round 14
// 205.243 us; speedup vs baseline: 1.3930x; 1.0134x over previous
//
#include <hip/hip_runtime.h>
#include <hip/hip_bf16.h>
#include <stdint.h>
#include <cmath>

typedef __attribute__((ext_vector_type(8))) short short8;
typedef __attribute__((ext_vector_type(4))) float f32x4;

#define D_MODEL 1024
#define S_LEN   2048
#define N_HEADS 16
#define HEAD_D  64
#define BATCH   2
#define NROWS   (BATCH * S_LEN)          // 4096
#define MLSTRIDE (NROWS * N_HEADS)       // 65536
#define LOG2E   1.4426950408889634f

__device__ __forceinline__ unsigned short f2bf(float f) {
  __hip_bfloat16 h = __float2bfloat16(f);
  return *reinterpret_cast<unsigned short*>(&h);
}

__device__ __forceinline__ float bf2f(unsigned short u) {
  unsigned int b = ((unsigned int)u) << 16;
  return *reinterpret_cast<float*>(&b);
}

__device__ __forceinline__ unsigned int pack2(unsigned short lo, unsigned short hi) {
  return (unsigned int)lo | ((unsigned int)hi << 16);
}

// async global->LDS, 16B per lane. LDS base must be wave-uniform; HW adds lane*16.
__device__ __forceinline__ void gload_lds16(const void* g, void* l) {
  auto gp = (const __attribute__((address_space(1))) unsigned int*)(uintptr_t)g;
  auto lp = (__attribute__((address_space(3))) unsigned int*)(unsigned int)(uintptr_t)l;
  __builtin_amdgcn_global_load_lds(gp, lp, 16, 0, 0);
}

// ---------------- cast fp32 -> bf16 (vectorized) ----------------
__global__ void cast_f32_bf16(const float* __restrict__ in, unsigned short* __restrict__ out, int n4) {
  int i = blockIdx.x * blockDim.x + threadIdx.x;
  if (i >= n4) return;
  float4 v = reinterpret_cast<const float4*>(in)[i];
  ushort4 o;
  o.x = f2bf(v.x); o.y = f2bf(v.y); o.z = f2bf(v.z); o.w = f2bf(v.w);
  reinterpret_cast<ushort4*>(out)[i] = o;
}

// ---------------- transpose + cast: out[C][R] = bf16(in[R][C]) ----------------
__global__ void transpose_cast(const float* __restrict__ in, unsigned short* __restrict__ out, int R, int C) {
  __shared__ float tile[32][33];
  int c0 = blockIdx.x * 32, r0 = blockIdx.y * 32;
  int tx = threadIdx.x, ty = threadIdx.y;  // blockDim (32,8)
#pragma unroll
  for (int j = 0; j < 32; j += 8)
    tile[ty + j][tx] = in[(size_t)(r0 + ty + j) * C + c0 + tx];
  __syncthreads();
#pragma unroll
  for (int j = 0; j < 32; j += 8)
    out[(size_t)(c0 + ty + j) * R + r0 + tx] = f2bf(tile[tx][ty + j]);
}

// ---------------- bf16 GEMM 128x128, C = A * BT^T ----------------
template <typename OutT>
__global__ __launch_bounds__(256) void gemm_bt(
    const unsigned short* __restrict__ A,
    const unsigned short* __restrict__ BT,
    OutT* __restrict__ C,
    int M, int N, int K)
{
  constexpr int BK = 32;
  __shared__ unsigned short As[128 * BK];
  __shared__ unsigned short Bs[128 * BK];
  const int tid = threadIdx.x;
  const int wave = tid >> 6, lane = tid & 63;
  const int l15 = lane & 15, l4 = lane >> 4;
  const int wr = wave >> 1, wc = wave & 1;
  const size_t m0 = (size_t)blockIdx.y * 128, n0 = (size_t)blockIdx.x * 128;

  f32x4 acc[4][4];
#pragma unroll
  for (int m = 0; m < 4; ++m)
#pragma unroll
    for (int n = 0; n < 4; ++n) acc[m][n] = 0.f;

  for (int k0 = 0; k0 < K; k0 += BK) {
    __syncthreads();
#pragma unroll
    for (int it = 0; it < 2; ++it) {
      const int base = it * 256 + wave * 64;         // wave-uniform chunk base
      const int chunk = base + lane;                  // per-lane chunk
      const int row = chunk >> 2, k8 = (chunk & 3) * 8;
      gload_lds16(A + (m0 + row) * K + k0 + k8, &As[base * 8]);
      gload_lds16(BT + (n0 + row) * K + k0 + k8, &Bs[base * 8]);
    }
    __syncthreads();
    short8 af[4], bfr[4];
#pragma unroll
    for (int m = 0; m < 4; ++m)
      af[m] = *reinterpret_cast<const short8*>(&As[(wr * 64 + m * 16 + l15) * BK + l4 * 8]);
#pragma unroll
    for (int n = 0; n < 4; ++n)
      bfr[n] = *reinterpret_cast<const short8*>(&Bs[(wc * 64 + n * 16 + l15) * BK + l4 * 8]);
#pragma unroll
    for (int m = 0; m < 4; ++m)
#pragma unroll
      for (int n = 0; n < 4; ++n)
        acc[m][n] = __builtin_amdgcn_mfma_f32_16x16x32_bf16(af[m], bfr[n], acc[m][n], 0, 0, 0);
  }

  // C layout: col = lane&15, row = (lane>>4)*4 + reg   [m89-verified]
#pragma unroll
  for (int m = 0; m < 4; ++m)
#pragma unroll
    for (int n = 0; n < 4; ++n)
#pragma unroll
      for (int r = 0; r < 4; ++r) {
        size_t row = m0 + wr * 64 + m * 16 + l4 * 4 + r;
        size_t col = n0 + wc * 64 + n * 16 + l15;
        if constexpr (sizeof(OutT) == 2)
          C[row * N + col] = (OutT)f2bf(acc[m][n][r]);
        else
          C[row * N + col] = acc[m][n][r];
      }
}

// ---------------- bf16 GEMM 64x128 (occupancy variant for small-N) ----------------
__global__ __launch_bounds__(256) void gemm_bt64(
    const unsigned short* __restrict__ A,
    const unsigned short* __restrict__ BT,
    float* __restrict__ C,
    int M, int N, int K)
{
  constexpr int BK = 32;
  __shared__ unsigned short As[64 * BK];
  __shared__ unsigned short Bs[128 * BK];
  const int tid = threadIdx.x;
  const int wave = tid >> 6, lane = tid & 63;
  const int l15 = lane & 15, l4 = lane >> 4;
  const int wr = wave >> 1, wc = wave & 1;   // 2x2 wave grid; wave tile 32x64
  const size_t m0 = (size_t)blockIdx.y * 64, n0 = (size_t)blockIdx.x * 128;

  f32x4 acc[2][4];
#pragma unroll
  for (int m = 0; m < 2; ++m)
#pragma unroll
    for (int n = 0; n < 4; ++n) acc[m][n] = 0.f;

  for (int k0 = 0; k0 < K; k0 += BK) {
    __syncthreads();
    {
      const int base = wave * 64;
      const int chunk = base + lane;
      const int row = chunk >> 2, k8 = (chunk & 3) * 8;
      gload_lds16(A + (m0 + row) * K + k0 + k8, &As[base * 8]);
    }
#pragma unroll
    for (int it = 0; it < 2; ++it) {
      const int base = it * 256 + wave * 64;
      const int chunk = base + lane;
      const int row = chunk >> 2, k8 = (chunk & 3) * 8;
      gload_lds16(BT + (n0 + row) * K + k0 + k8, &Bs[base * 8]);
    }
    __syncthreads();
    short8 af[2], bfr[4];
#pragma unroll
    for (int m = 0; m < 2; ++m)
      af[m] = *reinterpret_cast<const short8*>(&As[(wr * 32 + m * 16 + l15) * BK + l4 * 8]);
#pragma unroll
    for (int n = 0; n < 4; ++n)
      bfr[n] = *reinterpret_cast<const short8*>(&Bs[(wc * 64 + n * 16 + l15) * BK + l4 * 8]);
#pragma unroll
    for (int m = 0; m < 2; ++m)
#pragma unroll
      for (int n = 0; n < 4; ++n)
        acc[m][n] = __builtin_amdgcn_mfma_f32_16x16x32_bf16(af[m], bfr[n], acc[m][n], 0, 0, 0);
  }

#pragma unroll
  for (int m = 0; m < 2; ++m)
#pragma unroll
    for (int n = 0; n < 4; ++n)
#pragma unroll
      for (int r = 0; r < 4; ++r) {
        size_t row = m0 + wr * 32 + m * 16 + l4 * 4 + r;
        size_t col = n0 + wc * 64 + n * 16 + l15;
        C[row * N + col] = acc[m][n][r];
      }
}

// ---------------- causal flash attention, 2-way KV-split ----------------
// grid: (32, B*H, 2). block: 256 (4 waves), each wave owns 16 q rows.
// Vt is XOR-SWIZZLED (T2): V pair (kv,kv+1) of row d stored at column
// kv ^ (((d>>3)&7)<<3). Write banks: (36j + (r ^ (c<<2))) -> perfect 2-way
// (was 8-way: 288c = 0 mod 32 put 8 lanes on one bank -> the stable
// 1.24e7 SQ_LDS_BANK_CONFLICT). Read applies the same involution; key is
// a multiple of 8 elems = 16B so ds_read_b128 stays aligned+contiguous.
// Softmax in exp2 domain: log2e folded into Q prescale, exp2f everywhere,
// defer-max threshold 8*log2e. ml stores m in LOG2 domain (combine matches).
__global__ __launch_bounds__(256) void attn_kernel(
    const unsigned short* __restrict__ qkv,  // [B*S, 3*D] bf16
    unsigned short* __restrict__ ctx,        // split0 partial o (unnorm)
    unsigned short* __restrict__ part1,      // split1 partial o (unnorm)
    float2* __restrict__ ml)                 // [2][NROWS][H] (m_log2,l)
{
  constexpr int LDT = 72;  // padded row; rows stay 16B-aligned (144B)
  __shared__ unsigned short Ks[64 * LDT];   // K tile, then P tile (overlaid)
  __shared__ unsigned short Vt[64 * LDT];   // transposed+swizzled: Vt[d][kv^key]

  const int tid = threadIdx.x;
  const int wave = tid >> 6, lane = tid & 63;
  const int l15 = lane & 15, l4 = lane >> 4;
  const int bh = blockIdx.y;
  const int spl = blockIdx.z;
  const int qt = ((31 - (int)blockIdx.x) + ((bh >> 3) << 3)) & 31;  // CU-balance swizzle
  const int b = bh >> 4, h = bh & 15;
  const int q0 = qt * 64;
  const int nt = qt + 1;
  const int n0 = (nt + 1) >> 1;
  const int t_lo = spl ? n0 : 0;
  const int t_hi = spl ? nt : n0;
  if (t_lo >= t_hi) return;   // empty split (qt==0, spl==1); uniform per block

  const size_t rowstride = 3 * D_MODEL;
  const size_t bbase = (size_t)b * S_LEN;

  // Q fragments in registers, pre-scaled by (1/8)*log2e (exp2-domain softmax).
  short8 qf[2];
  {
    const int qrow = q0 + wave * 16 + l15;
    const unsigned short* qp = qkv + (bbase + qrow) * rowstride + h * HEAD_D;
    qf[0] = *reinterpret_cast<const short8*>(qp + l4 * 8);
    qf[1] = *reinterpret_cast<const short8*>(qp + 32 + l4 * 8);
    const float qs = 0.125f * LOG2E;
#pragma unroll
    for (int j = 0; j < 8; ++j) {
      qf[0][j] = (short)f2bf(bf2f((unsigned short)qf[0][j]) * qs);
      qf[1][j] = (short)f2bf(bf2f((unsigned short)qf[1][j]) * qs);
    }
  }

  f32x4 o[4];
#pragma unroll
  for (int nf = 0; nf < 4; ++nf) o[nf] = 0.f;
  float m_run[4], l_run[4];
#pragma unroll
  for (int r = 0; r < 4; ++r) { m_run[r] = -INFINITY; l_run[r] = 0.f; }

  // K staging indices: row sr_k = tid>>2, cols sck..sck+15
  const int sr_k = tid >> 2;
  const int sck  = (tid & 3) * 16;
  // V staging indices: rows kvr, kvr+1, cols a8..a8+7; swizzled column
  const int kvr = (tid >> 3) * 2;
  const int a8  = (tid & 7) * 8;
  const int vcol = kvr ^ ((tid & 7) << 3);   // kv-pair position after XOR swizzle

  const unsigned short* kbase = qkv + bbase * rowstride + h * HEAD_D + D_MODEL;
  const unsigned short* vbase = qkv + bbase * rowstride + h * HEAD_D + 2 * D_MODEL;

  // prologue: load tile t_lo K/V into registers
  short8 kr0, kr1, vr0, vr1;
  {
    const unsigned short* kp = kbase + (size_t)(t_lo * 64 + sr_k) * rowstride + sck;
    const unsigned short* vp = vbase + (size_t)(t_lo * 64 + kvr) * rowstride + a8;
    kr0 = *reinterpret_cast<const short8*>(kp);
    kr1 = *reinterpret_cast<const short8*>(kp + 8);
    vr0 = *reinterpret_cast<const short8*>(vp);
    vr1 = *reinterpret_cast<const short8*>(vp + rowstride);
  }

  for (int t = t_lo; t < t_hi; ++t) {
    const int kv0 = t * 64;
    __syncthreads();  // prev tile's consumers done with Ks(P)/Vt

    // write staged registers -> LDS
    *reinterpret_cast<short8*>(&Ks[sr_k * LDT + sck])     = kr0;
    *reinterpret_cast<short8*>(&Ks[sr_k * LDT + sck + 8]) = kr1;
#pragma unroll
    for (int j = 0; j < 8; ++j)
      *reinterpret_cast<unsigned int*>(&Vt[(a8 + j) * LDT + vcol]) =
          pack2((unsigned short)vr0[j], (unsigned short)vr1[j]);

    // issue next tile's loads (fly during compute below)
    if (t + 1 < t_hi) {
      const unsigned short* kp = kbase + (size_t)(kv0 + 64 + sr_k) * rowstride + sck;
      const unsigned short* vp = vbase + (size_t)(kv0 + 64 + kvr) * rowstride + a8;
      kr0 = *reinterpret_cast<const short8*>(kp);
      kr1 = *reinterpret_cast<const short8*>(kp + 8);
      vr0 = *reinterpret_cast<const short8*>(vp);
      vr1 = *reinterpret_cast<const short8*>(vp + rowstride);
    }
    __syncthreads();

    // S = Q K^T : 16(q) x 64(kv), B-frag from Ks rows
    f32x4 accs[4];
#pragma unroll
    for (int nf = 0; nf < 4; ++nf) accs[nf] = 0.f;
    __builtin_amdgcn_s_setprio(1);
#pragma unroll
    for (int nf = 0; nf < 4; ++nf) {
      short8 kf0 = *reinterpret_cast<const short8*>(&Ks[(nf * 16 + l15) * LDT + l4 * 8]);
      short8 kf1 = *reinterpret_cast<const short8*>(&Ks[(nf * 16 + l15) * LDT + 32 + l4 * 8]);
      accs[nf] = __builtin_amdgcn_mfma_f32_16x16x32_bf16(qf[0], kf0, accs[nf], 0, 0, 0);
      accs[nf] = __builtin_amdgcn_mfma_f32_16x16x32_bf16(qf[1], kf1, accs[nf], 0, 0, 0);
    }
    __builtin_amdgcn_s_setprio(0);

    // per-lane tile max (mask only on diagonal tile); scores in log2 domain
    float p[4][4], tm[4];
#pragma unroll
    for (int r = 0; r < 4; ++r) tm[r] = -INFINITY;
    if (t == qt) {
      const int qrow_base = q0 + wave * 16 + l4 * 4;
#pragma unroll
      for (int nf = 0; nf < 4; ++nf) {
        int kv = kv0 + nf * 16 + l15;
#pragma unroll
        for (int r = 0; r < 4; ++r) {
          float v = accs[nf][r];
          if (kv > qrow_base + r) v = -INFINITY;
          p[nf][r] = v;
          tm[r] = fmaxf(tm[r], v);
        }
      }
    } else {
#pragma unroll
      for (int nf = 0; nf < 4; ++nf)
#pragma unroll
        for (int r = 0; r < 4; ++r) {
          float v = accs[nf][r];
          p[nf][r] = v;
          tm[r] = fmaxf(tm[r], v);
        }
    }

    // T13 defer-max (threshold 8*log2e in log2 domain)
    int fastf = 1;
#pragma unroll
    for (int r = 0; r < 4; ++r)
      fastf &= (tm[r] <= m_run[r] + 11.5415603f) ? 1 : 0;
    if (!__all(fastf)) {
#pragma unroll
      for (int mset = 1; mset < 16; mset <<= 1)
#pragma unroll
        for (int r = 0; r < 4; ++r)
          tm[r] = fmaxf(tm[r], __shfl_xor(tm[r], mset));
      float corr[4];
#pragma unroll
      for (int r = 0; r < 4; ++r) {
        float mn = fmaxf(m_run[r], tm[r]);
        corr[r] = exp2f(m_run[r] - mn);
        m_run[r] = mn;
        l_run[r] *= corr[r];
      }
#pragma unroll
      for (int nf = 0; nf < 4; ++nf)
#pragma unroll
        for (int r = 0; r < 4; ++r)
          o[nf][r] *= corr[r];
    }

    // exp2 + per-lane l accumulation (no per-tile sum tree)
#pragma unroll
    for (int nf = 0; nf < 4; ++nf)
#pragma unroll
      for (int r = 0; r < 4; ++r)
        p[nf][r] = exp2f(p[nf][r] - m_run[r]);
#pragma unroll
    for (int r = 0; r < 4; ++r)
      l_run[r] += p[0][r] + p[1][r] + p[2][r] + p[3][r];

    // All waves' QK^T reads of Ks are complete before P overwrites it.
    __syncthreads();

    // P -> LDS (C-layout scatter) into the Ks buffer (overlay).
#pragma unroll
    for (int nf = 0; nf < 4; ++nf)
#pragma unroll
      for (int r = 0; r < 4; ++r)
        Ks[(wave * 16 + l4 * 4 + r) * LDT + nf * 16 + l15] = f2bf(p[nf][r]);

    // O += P V  (P rows wave-private; Vt read applies the same XOR key)
    __builtin_amdgcn_s_setprio(1);
#pragma unroll
    for (int c = 0; c < 2; ++c) {
      short8 pa = *reinterpret_cast<const short8*>(&Ks[(wave * 16 + l15) * LDT + c * 32 + l4 * 8]);
#pragma unroll
      for (int nf = 0; nf < 4; ++nf) {
        const int d = nf * 16 + l15;
        const int key8 = ((d >> 3) & 7) << 3;
        short8 vbf = *reinterpret_cast<const short8*>(&Vt[d * LDT + ((c * 32 + l4 * 8) ^ key8)]);
        o[nf] = __builtin_amdgcn_mfma_f32_16x16x32_bf16(pa, vbf, o[nf], 0, 0, 0);
      }
    }
    __builtin_amdgcn_s_setprio(0);
  }

  // final l reduction across the 16-lane row group (once per block)
#pragma unroll
  for (int mset = 1; mset < 16; mset <<= 1)
#pragma unroll
    for (int r = 0; r < 4; ++r)
      l_run[r] += __shfl_xor(l_run[r], mset);

  // epilogue: write UNNORMALIZED o + (m_log2,l)
  unsigned short* dst = spl ? part1 : ctx;
#pragma unroll
  for (int r = 0; r < 4; ++r) {
    const int q = q0 + wave * 16 + l4 * 4 + r;
    unsigned short* op = dst + (bbase + q) * D_MODEL + h * HEAD_D;
#pragma unroll
    for (int nf = 0; nf < 4; ++nf)
      op[nf * 16 + l15] = f2bf(o[nf][r]);
  }
  if (l15 == 0) {
#pragma unroll
    for (int r = 0; r < 4; ++r) {
      const int q = q0 + wave * 16 + l4 * 4 + r;
      float2 v; v.x = m_run[r]; v.y = l_run[r];
      ml[spl * MLSTRIDE + ((int)bbase + q) * N_HEADS + h] = v;
    }
  }
}

// ---------------- combine the two KV-splits (m in log2 domain) ----------------
__global__ __launch_bounds__(256) void attn_combine(
    const unsigned short* __restrict__ o1,
    const float2* __restrict__ ml,
    unsigned short* __restrict__ ctx)
{
  const int tid = threadIdx.x;
  const int pi = blockIdx.x * 32 + (tid >> 3);   // (row,head) pair
  const int lane8 = tid & 7;
  const int r = pi >> 4, h = pi & 15;
  const int s = r & (S_LEN - 1);
  const int qt = s >> 6;
  const size_t off = (size_t)r * D_MODEL + h * HEAD_D + lane8 * 8;
  short8 a = *reinterpret_cast<const short8*>(&ctx[off]);
  float2 ml0 = ml[r * N_HEADS + h];
  short8 outv;
  if (qt == 0) {
    float inv = 1.f / ml0.y;
#pragma unroll
    for (int j = 0; j < 8; ++j) outv[j] = (short)f2bf(bf2f((unsigned short)a[j]) * inv);
  } else {
    short8 bv = *reinterpret_cast<const short8*>(&o1[off]);
    float2 ml1 = ml[MLSTRIDE + r * N_HEADS + h];
    float M = fmaxf(ml0.x, ml1.x);
    float w0 = exp2f(ml0.x - M), w1 = exp2f(ml1.x - M);
    float inv = 1.f / (w0 * ml0.y + w1 * ml1.y);
#pragma unroll
    for (int j = 0; j < 8; ++j)
      outv[j] = (short)f2bf((bf2f((unsigned short)a[j]) * w0 + bf2f((unsigned short)bv[j]) * w1) * inv);
  }
  *reinterpret_cast<short8*>(&ctx[off]) = outv;
}

// ---------------- launch ----------------
extern "C" void kernel_launch(void* const* d_in, const int* in_sizes, int n_in,
                              void* d_out, int out_size, void* d_ws, size_t ws_size,
                              hipStream_t stream) {
  const float* x     = (const float*)d_in[0];
  const float* w_qkv = (const float*)d_in[1];
  const float* w_out = (const float*)d_in[2];
  float* out = (float*)d_out;

  char* p = (char*)d_ws;
  unsigned short* xb    = (unsigned short*)p; p += (size_t)4096 * 1024 * 2;  // dead after qkv GEMM -> part1
  unsigned short* wqkvT = (unsigned short*)p; p += (size_t)3072 * 1024 * 2;  // dead after qkv GEMM -> ml
  unsigned short* woutT = (unsigned short*)p; p += (size_t)1024 * 1024 * 2;
  unsigned short* qkv   = (unsigned short*)p; p += (size_t)4096 * 3072 * 2;
  unsigned short* ctx   = (unsigned short*)p; p += (size_t)4096 * 1024 * 2;

  unsigned short* part1 = xb;                  // 8.4 MB, fits exactly
  float2*         ml    = (float2*)wqkvT;      // 1 MB, fits

  cast_f32_bf16<<<4096, 256, 0, stream>>>(x, xb, 4096 * 1024 / 4);
  transpose_cast<<<dim3(3072 / 32, 1024 / 32), dim3(32, 8), 0, stream>>>(w_qkv, wqkvT, 1024, 3072);
  transpose_cast<<<dim3(1024 / 32, 1024 / 32), dim3(32, 8), 0, stream>>>(w_out, woutT, 1024, 1024);
  gemm_bt<unsigned short><<<dim3(3072 / 128, 4096 / 128), 256, 0, stream>>>(xb, wqkvT, qkv, 4096, 3072, 1024);
  attn_kernel<<<dim3(S_LEN / 64, BATCH * N_HEADS, 2), 256, 0, stream>>>(qkv, ctx, part1, ml);
  attn_combine<<<(NROWS * N_HEADS) / 32, 256, 0, stream>>>(part1, ml, ctx);
  gemm_bt64<<<dim3(1024 / 128, 4096 / 64), 256, 0, stream>>>(ctx, woutT, out, 4096, 1024, 1024);
}